// Round 13
// baseline (158.784 us; speedup 1.0000x reference)
//
#include <hip/hip_runtime.h>

// FullAttention fused pipeline for MI355X (gfx950).
// B=4 S=2048 D=512 H=8 DK=DV=64.
// Round 13: resubmit of round 12 (infra transport failure, kernel never ran).
// 128-wide GEMM tiles. proj 128x128 (4 waves x 64x64 quadrant,
// 32 MFMA/K-step/wave, per-wave fragment-major epilogue), fc 128x64.
// attn/pack/ln identical to round 11 (best composite).

#define B_ 4
#define S_ 2048
#define D_ 512
#define H_ 8

typedef __attribute__((ext_vector_type(8))) short short8_t;
typedef __attribute__((ext_vector_type(4))) short short4_t;
typedef __attribute__((ext_vector_type(4))) float f32x4;
typedef __attribute__((ext_vector_type(16))) float f32x16;
typedef __attribute__((ext_vector_type(4))) unsigned u32x4;
typedef __attribute__((ext_vector_type(2))) unsigned u32x2;

__device__ __forceinline__ short f2bf(float f) {
    unsigned u = __builtin_bit_cast(unsigned, f);
    u += 0x7fff + ((u >> 16) & 1);   // RNE
    return (short)(u >> 16);
}

// pack two f32 -> two bf16 (truncation) via one v_perm_b32
__device__ __forceinline__ unsigned pk2(float a, float b) {
    return __builtin_amdgcn_perm(__builtin_bit_cast(unsigned, b),
                                 __builtin_bit_cast(unsigned, a), 0x07060302u);
}

__device__ __forceinline__ float bf2f(short v) {
    return __builtin_bit_cast(float, (unsigned)((unsigned short)v) << 16);
}

// 4 bytes -> 4 bits (bit i = byte i nonzero)
__device__ __forceinline__ unsigned nib4(unsigned w4) {
    unsigned t = (w4 & 0x7f7f7f7fu) + 0x7f7f7f7fu;
    t |= w4;
    return (((t >> 7) & 0x01010101u) * 0x01020408u) >> 24;
}

// ---------------------------------------------------------------------------
// Kernel 1: mask detect (bool-1B vs int32) + bit-pack INVERTED (bit=KEEP),
// relayout to [(b*32+kt)*2048 + q] u64 words. Vectorized loads.
// ---------------------------------------------------------------------------
__global__ __launch_bounds__(256) void pack_mask_kernel(const void* __restrict__ mask,
                                                        unsigned* __restrict__ bits) {
    __shared__ int isBool;
    if (threadIdx.x == 0) isBool = 0;
    __syncthreads();
    const unsigned char* bytes = (const unsigned char*)mask;
    if (threadIdx.x < 64) {
        if (bytes[threadIdx.x * 4 + 1] | bytes[threadIdx.x * 4 + 2] | bytes[threadIdx.x * 4 + 3])
            isBool = 1;
    }
    __syncthreads();
    int t = blockIdx.x * 256 + threadIdx.x;          // 0..524287
    int half = t & 1, q = (t >> 1) & 2047, kt = (t >> 12) & 31, b = t >> 17;
    size_t src = ((size_t)(b * 2048 + q)) * 2048 + kt * 64 + half * 32;  // element idx
    unsigned v = 0;
    if (isBool) {
        const u32x4* p = (const u32x4*)(bytes + src);     // 32 bytes = 2 x 16B
        u32x4 w0 = p[0], w1 = p[1];
        v = nib4(w0[0]) | (nib4(w0[1]) << 4) | (nib4(w0[2]) << 8) | (nib4(w0[3]) << 12) |
            (nib4(w1[0]) << 16) | (nib4(w1[1]) << 20) | (nib4(w1[2]) << 24) | (nib4(w1[3]) << 28);
    } else {
        const u32x4* p = (const u32x4*)((const int*)mask + src);  // 32 ints = 8 x 16B
        #pragma unroll
        for (int j = 0; j < 8; ++j) {
            u32x4 wv = p[j];
            v |= ((wv[0] ? 1u : 0u) | (wv[1] ? 2u : 0u) | (wv[2] ? 4u : 0u) | (wv[3] ? 8u : 0u)) << (j * 4);
        }
    }
    bits[(((size_t)(b * 32 + kt)) * 2048 + q) * 2 + half] = ~v;   // KEEP bits
}

// ---------------------------------------------------------------------------
// Kernel 2: QKV projection, 128x128 tile, BK=64. grid=(64, 4, 3).
// 4 waves, each owns a 64x64 quadrant (wm = (w>>1)*64, wn = (w&1)*64).
// Q out: [b][h][s][dk] bf16 (scaled log2e/8).
// K out: fragment-major K'[(b,h)][kt][ks][hi][key]x8 (16B units).
// V out: fragment-major V'[(b,h)][kt][kb][hi][dv]x8 (16B units).
// K/V epilogue is per-wave: each quadrant is one complete (kt,h) 64x64 block.
// ---------------------------------------------------------------------------
__global__ __launch_bounds__(256) void proj_kernel(
    const float* __restrict__ inQ, const float* __restrict__ inK, const float* __restrict__ inV,
    const float* __restrict__ wq, const float* __restrict__ wk, const float* __restrict__ wv,
    short* __restrict__ Qp, short* __restrict__ Kp, short* __restrict__ Vp) {
    __shared__ short As[128 * 64];   // A tile [row][k] swizzled (16KB)
    __shared__ short Bs[128 * 64];   // B tile [n][k] swizzled (16KB)
    const int z = blockIdx.z;
    const float* A = (z == 0) ? inQ : ((z == 1) ? inK : inV);
    const float* W = (z == 0) ? wq : ((z == 1) ? wk : wv);
    short* O = (z == 0) ? Qp : ((z == 1) ? Kp : Vp);
    const float scale = (z == 0) ? 0.125f * 1.44269504f : 1.0f;   // log2e folded into Q
    const int bm = blockIdx.x * 128, bn = blockIdx.y * 128;
    const int tid = threadIdx.x, lane = tid & 63, wv_ = tid >> 6;
    const int wm = (wv_ >> 1) * 64, wn = (wv_ & 1) * 64;
    f32x4 acc[4][4] = {};

    for (int k0 = 0; k0 < 512; k0 += 64) {
        __syncthreads();
        // stage A: 128 rows x 64 k, pair-packed bf16; 32 elems/thread
        #pragma unroll
        for (int it = 0; it < 8; ++it) {
            int g = tid + it * 256;
            int r = g >> 4, c4 = (g & 15) * 4;
            f32x4 v = *(const f32x4*)(A + (size_t)(bm + r) * 512 + k0 + c4);
            u32x2 u = { pk2(v.x, v.y), pk2(v.z, v.w) };
            *(u32x2*)((char*)As + r * 128 + ((c4 * 2) ^ ((r & 7) << 4))) = u;
        }
        // stage B transposed: 64 k x 128 n -> [n][k]; k-pairs as u32
        #pragma unroll
        for (int it = 0; it < 4; ++it) {
            int g = tid + it * 256;
            int kp = g >> 5, n4 = (g & 31) * 4;
            const float* wrow = W + (size_t)(k0 + 2 * kp) * 512 + bn + n4;
            f32x4 va = *(const f32x4*)(wrow);
            f32x4 vb = *(const f32x4*)(wrow + 512);
            #pragma unroll
            for (int j = 0; j < 4; ++j) {
                int n = n4 + j;
                *(unsigned*)((char*)Bs + n * 128 + ((4 * kp) ^ ((n & 7) << 4))) = pk2(va[j], vb[j]);
            }
        }
        __syncthreads();
        #pragma unroll
        for (int kk = 0; kk < 2; ++kk) {
            short8_t af[4], bfr[4];
            #pragma unroll
            for (int rf = 0; rf < 4; ++rf) {
                int row = wm + rf * 16 + (lane & 15);
                af[rf] = *(const short8_t*)((const char*)As + row * 128 +
                          ((kk * 64 + ((lane >> 4) * 16)) ^ ((row & 7) << 4)));
            }
            #pragma unroll
            for (int cf = 0; cf < 4; ++cf) {
                int n = wn + cf * 16 + (lane & 15);
                bfr[cf] = *(const short8_t*)((const char*)Bs + n * 128 +
                           ((kk * 64 + ((lane >> 4) * 16)) ^ ((n & 7) << 4)));
            }
            __builtin_amdgcn_s_setprio(1);
            #pragma unroll
            for (int rf = 0; rf < 4; ++rf)
                #pragma unroll
                for (int cf = 0; cf < 4; ++cf)
                    acc[rf][cf] = __builtin_amdgcn_mfma_f32_16x16x32_bf16(af[rf], bfr[cf], acc[rf][cf], 0, 0, 0);
            __builtin_amdgcn_s_setprio(0);
        }
    }

    if (z == 0) {
        // Q: direct [b][h][s][dk]
        #pragma unroll
        for (int rf = 0; rf < 4; ++rf)
            #pragma unroll
            for (int cf = 0; cf < 4; ++cf)
                #pragma unroll
                for (int r = 0; r < 4; ++r) {
                    int row = bm + wm + rf * 16 + (lane >> 4) * 4 + r;
                    int col = bn + wn + cf * 16 + (lane & 15);
                    size_t idx = ((((size_t)(row >> 11)) * 8 + (col >> 6)) * 2048 + (row & 2047)) * 64 + (col & 63);
                    O[idx] = f2bf(acc[rf][cf][r] * scale);
                }
    } else {
        // K/V per-wave epilogue: this wave's 64x64 quadrant = one (kt,h) block.
        __syncthreads();   // all waves past final mfma; LDS reusable
        short* reg = ((wv_ < 2) ? As : Bs) + (wv_ & 1) * 4096;
        const int row0 = bm + wm;                     // 64-aligned global row
        const int bb = row0 >> 11, kt = (row0 & 2047) >> 6, hh = (bn + wn) >> 6;
        const size_t base = ((size_t)(bb * 8 + hh)) * 131072 + (size_t)kt * 4096;
        if (z == 1) {
            // K: stage [key][dk] swizzled
            #pragma unroll
            for (int rf = 0; rf < 4; ++rf)
                #pragma unroll
                for (int cf = 0; cf < 4; ++cf)
                    #pragma unroll
                    for (int r = 0; r < 4; ++r) {
                        int key = rf * 16 + (lane >> 4) * 4 + r;
                        int dk = cf * 16 + (lane & 15);
                        *(short*)((char*)reg + key * 128 + ((dk * 2) ^ ((key & 7) << 4))) = f2bf(acc[rf][cf][r]);
                    }
        } else {
            // V: stage transposed [dv][key] swizzled
            #pragma unroll
            for (int rf = 0; rf < 4; ++rf)
                #pragma unroll
                for (int cf = 0; cf < 4; ++cf)
                    #pragma unroll
                    for (int r = 0; r < 4; ++r) {
                        int key = rf * 16 + (lane >> 4) * 4 + r;
                        int dv = cf * 16 + (lane & 15);
                        *(short*)((char*)reg + dv * 128 + ((key * 2) ^ ((dv & 7) << 4))) = f2bf(acc[rf][cf][r]);
                    }
        }
        asm volatile("s_waitcnt lgkmcnt(0)" ::: "memory");   // wave-local LDS
        // fragment-major store: unit u = [blk](2b)[hi](1b)[row](6b), 16B each
        #pragma unroll
        for (int j = 0; j < 8; ++j) {
            int u = j * 64 + lane;
            int blk = u >> 7, h2 = (u >> 6) & 1, rr = u & 63;
            short8_t v8 = *(const short8_t*)((const char*)reg + rr * 128 +
                           ((blk * 32 + h2 * 16) ^ ((rr & 7) << 4)));
            *(short8_t*)(O + base + (size_t)u * 8) = v8;
        }
    }
}

// ---------------------------------------------------------------------------
// Kernel 3: barrier-free-loop flash attention with in-block split-KV.
// Block = 32 q-rows; wave w handles K-tiles [8w, 8w+8); LDS l-weighted merge.
// grid=(64, 8, 4) = 2048 blocks = 8 blocks/CU.
// ---------------------------------------------------------------------------
__global__ __launch_bounds__(256, 4) void attn_kernel(
    const short* __restrict__ Qp, const short* __restrict__ Kf, const short* __restrict__ Vf,
    const unsigned long long* __restrict__ mbits64, short* __restrict__ ctx) {
    __shared__ short Pw_all[4][2048];    // per-wave normalized partial (16KB)
    __shared__ float l_lds[4][32];
    // XCD-clustered remap: flat%8 ~ XCD; each XCD owns 4 whole (b,h) groups.
    int flat = blockIdx.x + 64 * (blockIdx.y + 8 * blockIdx.z);   // 0..2047
    int x8 = flat & 7, s = flat >> 3;                             // s: 0..255
    int bh = x8 * 4 + (s >> 6);                                   // 0..31
    int qi = s & 63;                                              // 0..63
    const int b = bh >> 3, h = bh & 7;
    const int tid = threadIdx.x, lane = tid & 63, w = tid >> 6;
    const int hi = lane >> 5, r31 = lane & 31;
    const size_t hb = ((size_t)bh) * 131072;
    const int qw = qi * 32;
    const int q_lane = qw + r31;
    const int t_beg = w * 8, t_end = t_beg + 8;

    short8_t qf[4];
    #pragma unroll
    for (int ks = 0; ks < 4; ++ks)
        qf[ks] = *(const short8_t*)(Qp + hb + (size_t)q_lane * 64 + ks * 16 + hi * 8);

    const short* Kb_ = Kf + hb + hi * 512 + r31 * 8;
    const short* Vb_ = Vf + hb + hi * 512 + r31 * 8;
    const unsigned long long* mrow = mbits64 + (size_t)b * 65536 + q_lane;

    f32x16 o0 = {}, o1 = {};
    float l_run = 0.f;

    for (int kt = t_beg; kt < t_end; ++kt) {
        const short* kp = Kb_ + (size_t)kt * 4096;
        unsigned long long wmx = mrow[(size_t)kt * 2048] >> (hi * 4);
        unsigned kl = (unsigned)wmx, kh = (unsigned)(wmx >> 32);

        // QK^T (log2 domain via Q scale)
        f32x16 s0 = {}, s1 = {};
        __builtin_amdgcn_s_setprio(1);
        #pragma unroll
        for (int ks = 0; ks < 4; ++ks) {
            short8_t kf0 = *(const short8_t*)(kp + ks * 1024);
            short8_t kf1 = *(const short8_t*)(kp + ks * 1024 + 256);
            s0 = __builtin_amdgcn_mfma_f32_32x32x16_bf16(kf0, qf[ks], s0, 0, 0, 0);
            s1 = __builtin_amdgcn_mfma_f32_32x32x16_bf16(kf1, qf[ks], s1, 0, 0, 0);
        }
        __builtin_amdgcn_s_setprio(0);

        // p = exp2(s) & keep, in-place; 4-way sum trees
        float r4[4] = { 0.f, 0.f, 0.f, 0.f };
        #pragma unroll
        for (int reg = 0; reg < 16; ++reg) {
            const int pos = (reg >> 2) * 8 + (reg & 3);
            float e0 = __builtin_amdgcn_exp2f(s0[reg]);
            float e1 = __builtin_amdgcn_exp2f(s1[reg]);
            unsigned k0b = (unsigned)__builtin_amdgcn_sbfe((int)kl, pos, 1);
            unsigned k1b = (unsigned)__builtin_amdgcn_sbfe((int)kh, pos, 1);
            float v0 = __builtin_bit_cast(float, __builtin_bit_cast(unsigned, e0) & k0b);
            float v1 = __builtin_bit_cast(float, __builtin_bit_cast(unsigned, e1) & k1b);
            s0[reg] = v0; s1[reg] = v1;
            r4[reg & 3] += v0 + v1;
        }
        float rs = (r4[0] + r4[1]) + (r4[2] + r4[3]);
        rs += __shfl_xor(rs, 32, 64);
        l_run += rs;

        // PV: O^T += V^T . P^T
        const short* vp = Vb_ + (size_t)kt * 4096;
        #pragma unroll
        for (int kb = 0; kb < 4; ++kb) {
            const int e = (kb & 1) * 8;
            unsigned c0 = (kb < 2) ? pk2(s0[e + 0], s0[e + 1]) : pk2(s1[e + 0], s1[e + 1]);
            unsigned c1 = (kb < 2) ? pk2(s0[e + 2], s0[e + 3]) : pk2(s1[e + 2], s1[e + 3]);
            unsigned c2 = (kb < 2) ? pk2(s0[e + 4], s0[e + 5]) : pk2(s1[e + 4], s1[e + 5]);
            unsigned c3 = (kb < 2) ? pk2(s0[e + 6], s0[e + 7]) : pk2(s1[e + 6], s1[e + 7]);
#if __has_builtin(__builtin_amdgcn_permlane32_swap)
            u32x2 r02 = __builtin_amdgcn_permlane32_swap(c0, c2, false, false);
            u32x2 r13 = __builtin_amdgcn_permlane32_swap(c1, c3, false, false);
            u32x4 bw = { r02[0], r13[0], r02[1], r13[1] };
#else
            unsigned x0 = __shfl_xor(c0, 32, 64), x1 = __shfl_xor(c1, 32, 64);
            unsigned x2 = __shfl_xor(c2, 32, 64), x3 = __shfl_xor(c3, 32, 64);
            unsigned w0 = hi ? x2 : c0, w1 = hi ? x3 : c1;
            unsigned w2 = hi ? c2 : x0, w3 = hi ? c3 : x1;
            u32x4 bw = { w0, w1, w2, w3 };
#endif
            short8_t pb = __builtin_bit_cast(short8_t, bw);
            short8_t vf0 = *(const short8_t*)(vp + kb * 1024);
            short8_t vf1 = *(const short8_t*)(vp + kb * 1024 + 256);
            __builtin_amdgcn_s_setprio(1);
            o0 = __builtin_amdgcn_mfma_f32_32x32x16_bf16(vf0, pb, o0, 0, 0, 0);
            o1 = __builtin_amdgcn_mfma_f32_32x32x16_bf16(vf1, pb, o1, 0, 0, 0);
            __builtin_amdgcn_s_setprio(0);
        }
    }

    // per-wave epilogue: normalize + transpose into LDS, post l
    float invl = 1.0f / fmaxf(l_run, 1e-37f);
    short* Pw = Pw_all[w];
    #pragma unroll
    for (int dvb = 0; dvb < 2; ++dvb)
        #pragma unroll
        for (int g = 0; g < 4; ++g) {
            short4_t v4;
            #pragma unroll
            for (int t = 0; t < 4; ++t) {
                float val = (dvb ? o1[g * 4 + t] : o0[g * 4 + t]) * invl;
                v4[t] = f2bf(val);
            }
            int dv0 = dvb * 32 + g * 8 + hi * 4;
            *(short4_t*)((char*)Pw + r31 * 128 + ((dv0 * 2) ^ ((r31 & 7) << 4))) = v4;
        }
    if (hi == 0) l_lds[w][r31] = l_run;
    __syncthreads();

    // block epilogue: l-weighted merge of the 4 wave partials -> ctx
    const int q = tid >> 3, j = tid & 7;
    float acc8[8] = {};
    float wsum = 0.f;
    #pragma unroll
    for (int ww = 0; ww < 4; ++ww) {
        float lw = l_lds[ww][q];
        wsum += lw;
        short8_t v8 = *(const short8_t*)((const char*)Pw_all[ww] + q * 128 + ((j * 16) ^ ((q & 7) << 4)));
        #pragma unroll
        for (int e = 0; e < 8; ++e)
            acc8[e] += bf2f(v8[e]) * lw;
    }
    float inv = 1.f / fmaxf(wsum, 1e-37f);
    u32x4 ov = { pk2(acc8[0] * inv, acc8[1] * inv), pk2(acc8[2] * inv, acc8[3] * inv),
                 pk2(acc8[4] * inv, acc8[5] * inv), pk2(acc8[6] * inv, acc8[7] * inv) };
    *(short8_t*)(ctx + ((size_t)(b * 2048 + qw + q)) * 512 + h * 64 + j * 8) =
        __builtin_bit_cast(short8_t, ov);
}

// ---------------------------------------------------------------------------
// Kernel 4: FC + residual, 128x64 tile, BK=64. grid=(64, 8).
// 4 waves, each owns 64x32 (wm=(w>>1)*64, wn=(w&1)*32).
// ---------------------------------------------------------------------------
__global__ __launch_bounds__(256) void fc_kernel(
    const short* __restrict__ ctx, const float* __restrict__ wfc,
    const float* __restrict__ inQ, float* __restrict__ xbuf) {
    __shared__ short As[128 * 64];   // 16KB
    __shared__ short Bs[64 * 64];    // 8KB
    const int bm = blockIdx.x * 128, bn = blockIdx.y * 64;
    const int tid = threadIdx.x, lane = tid & 63, wv_ = tid >> 6;
    const int wm = (wv_ >> 1) * 64, wn = (wv_ & 1) * 32;
    f32x4 acc[4][2] = {};

    for (int k0 = 0; k0 < 512; k0 += 64) {
        __syncthreads();
        // stage A (bf16 ctx): 128 rows x 64 k; short8 groups
        #pragma unroll
        for (int it = 0; it < 4; ++it) {
            int g = tid + it * 256;
            int r = g >> 3, c8 = (g & 7) * 8;
            short8_t v = *(const short8_t*)(ctx + (size_t)(bm + r) * 512 + k0 + c8);
            *(short8_t*)((char*)As + r * 128 + ((c8 * 2) ^ ((r & 7) << 4))) = v;
        }
        // stage B transposed: 64 k x 64 n
        #pragma unroll
        for (int it = 0; it < 2; ++it) {
            int g = tid + it * 256;
            int kp = g >> 4, n4 = (g & 15) * 4;
            const float* wrow = wfc + (size_t)(k0 + 2 * kp) * 512 + bn + n4;
            f32x4 va = *(const f32x4*)(wrow);
            f32x4 vb = *(const f32x4*)(wrow + 512);
            #pragma unroll
            for (int j = 0; j < 4; ++j) {
                int n = n4 + j;
                *(unsigned*)((char*)Bs + n * 128 + ((4 * kp) ^ ((n & 7) << 4))) = pk2(va[j], vb[j]);
            }
        }
        __syncthreads();
        #pragma unroll
        for (int kk = 0; kk < 2; ++kk) {
            short8_t af[4], bfr[2];
            #pragma unroll
            for (int rf = 0; rf < 4; ++rf) {
                int row = wm + rf * 16 + (lane & 15);
                af[rf] = *(const short8_t*)((const char*)As + row * 128 +
                          ((kk * 64 + ((lane >> 4) * 16)) ^ ((row & 7) << 4)));
            }
            #pragma unroll
            for (int cf = 0; cf < 2; ++cf) {
                int n = wn + cf * 16 + (lane & 15);
                bfr[cf] = *(const short8_t*)((const char*)Bs + n * 128 +
                           ((kk * 64 + ((lane >> 4) * 16)) ^ ((n & 7) << 4)));
            }
            __builtin_amdgcn_s_setprio(1);
            #pragma unroll
            for (int rf = 0; rf < 4; ++rf)
                #pragma unroll
                for (int cf = 0; cf < 2; ++cf)
                    acc[rf][cf] = __builtin_amdgcn_mfma_f32_16x16x32_bf16(af[rf], bfr[cf], acc[rf][cf], 0, 0, 0);
            __builtin_amdgcn_s_setprio(0);
        }
    }
    #pragma unroll
    for (int rf = 0; rf < 4; ++rf)
        #pragma unroll
        for (int cf = 0; cf < 2; ++cf)
            #pragma unroll
            for (int r = 0; r < 4; ++r) {
                int row = bm + wm + rf * 16 + (lane >> 4) * 4 + r;
                int col = bn + wn + cf * 16 + (lane & 15);
                size_t idx = (size_t)row * 512 + col;
                xbuf[idx] = acc[rf][cf][r] + inQ[idx];
            }
}

// ---------------------------------------------------------------------------
// Kernel 5: LayerNorm over D=512. Wave-per-row, no LDS, no barriers.
// grid=2048, 4 rows/block.
// ---------------------------------------------------------------------------
__global__ __launch_bounds__(256) void ln_kernel(
    const float* __restrict__ x, const float* __restrict__ gamma,
    const float* __restrict__ beta, float* __restrict__ out) {
    const int w = threadIdx.x >> 6, lane = threadIdx.x & 63;
    const int row = blockIdx.x * 4 + w;
    const f32x4* xr = (const f32x4*)(x + (size_t)row * 512);
    f32x4 a = xr[lane * 2], bb = xr[lane * 2 + 1];
    float s = (a.x + a.y) + (a.z + a.w) + (bb.x + bb.y) + (bb.z + bb.w);
    float sq = a.x * a.x + a.y * a.y + a.z * a.z + a.w * a.w +
               bb.x * bb.x + bb.y * bb.y + bb.z * bb.z + bb.w * bb.w;
    #pragma unroll
    for (int off = 32; off; off >>= 1) {
        s += __shfl_xor(s, off, 64);
        sq += __shfl_xor(sq, off, 64);
    }
    float mean = s * (1.f / 512.f);
    float var = sq * (1.f / 512.f) - mean * mean;
    float inv = rsqrtf(var + 1e-5f);
    const f32x4* gr = (const f32x4*)gamma;
    const f32x4* br = (const f32x4*)beta;
    f32x4 g0 = gr[lane * 2], g1 = gr[lane * 2 + 1];
    f32x4 b0 = br[lane * 2], b1 = br[lane * 2 + 1];
    f32x4 o0, o1;
    o0.x = (a.x - mean) * inv * g0.x + b0.x;
    o0.y = (a.y - mean) * inv * g0.y + b0.y;
    o0.z = (a.z - mean) * inv * g0.z + b0.z;
    o0.w = (a.w - mean) * inv * g0.w + b0.w;
    o1.x = (bb.x - mean) * inv * g1.x + b1.x;
    o1.y = (bb.y - mean) * inv * g1.y + b1.y;
    o1.z = (bb.z - mean) * inv * g1.z + b1.z;
    o1.w = (bb.w - mean) * inv * g1.w + b1.w;
    f32x4* orow = (f32x4*)(out + (size_t)row * 512);
    orow[lane * 2] = o0;
    orow[lane * 2 + 1] = o1;
}

// ---------------------------------------------------------------------------
extern "C" void kernel_launch(void* const* d_in, const int* in_sizes, int n_in,
                              void* d_out, int out_size, void* d_ws, size_t ws_size,
                              hipStream_t stream) {
    const float* inQ = (const float*)d_in[0];
    const float* inK = (const float*)d_in[1];
    const float* inV = (const float*)d_in[2];
    const void* mask = d_in[3];
    const float* wq = (const float*)d_in[4];
    const float* wk = (const float*)d_in[5];
    const float* wv = (const float*)d_in[6];
    const float* wfc = (const float*)d_in[7];
    const float* gamma = (const float*)d_in[8];
    const float* beta = (const float*)d_in[9];
    float* out = (float*)d_out;
    char* ws = (char*)d_ws;

    short* Qp = (short*)(ws);                          // 8 MB
    short* Kp = (short*)(ws + (size_t)(8 << 20));      // 8 MB, fragment-major
    short* Vp = (short*)(ws + (size_t)(16 << 20));     // 8 MB, fragment-major
    short* ctx = (short*)(ws + (size_t)(24 << 20));    // 8 MB
    unsigned* mbits = (unsigned*)(ws + (size_t)(32 << 20)); // 2 MB
    float* xbuf = (float*)(ws);                        // 16 MB, reuses Qp/Kp (dead after attn)

    pack_mask_kernel<<<2048, 256, 0, stream>>>(mask, mbits);
    proj_kernel<<<dim3(64, 4, 3), 256, 0, stream>>>(inQ, inK, inV, wq, wk, wv, Qp, Kp, Vp);
    attn_kernel<<<dim3(64, 8, 4), 256, 0, stream>>>(
        Qp, Kp, Vp, (const unsigned long long*)mbits, ctx);
    fc_kernel<<<dim3(64, 8), 256, 0, stream>>>(ctx, wfc, inQ, xbuf);
    ln_kernel<<<2048, 256, 0, stream>>>(xbuf, gamma, beta, out);
}

// Round 14
// 144.137 us; speedup vs baseline: 1.1016x; 1.1016x over previous
//
#include <hip/hip_runtime.h>

// FullAttention fused pipeline for MI355X (gfx950).
// B=4 S=2048 D=512 H=8 DK=DV=64.
// Round 14: proj reverted to 64x64 tile (round-11 version; 128^2 hit the
// VGPR>128 occupancy cliff at 148 regs -> 11% occ, 2x slower). fc kept at
// 128x64 (validated in round 13). attn/pack/ln unchanged (best composite).

#define B_ 4
#define S_ 2048
#define D_ 512
#define H_ 8

typedef __attribute__((ext_vector_type(8))) short short8_t;
typedef __attribute__((ext_vector_type(4))) short short4_t;
typedef __attribute__((ext_vector_type(4))) float f32x4;
typedef __attribute__((ext_vector_type(16))) float f32x16;
typedef __attribute__((ext_vector_type(4))) unsigned u32x4;
typedef __attribute__((ext_vector_type(2))) unsigned u32x2;

__device__ __forceinline__ short f2bf(float f) {
    unsigned u = __builtin_bit_cast(unsigned, f);
    u += 0x7fff + ((u >> 16) & 1);   // RNE
    return (short)(u >> 16);
}

// pack two f32 -> two bf16 (truncation) via one v_perm_b32
__device__ __forceinline__ unsigned pk2(float a, float b) {
    return __builtin_amdgcn_perm(__builtin_bit_cast(unsigned, b),
                                 __builtin_bit_cast(unsigned, a), 0x07060302u);
}

__device__ __forceinline__ float bf2f(short v) {
    return __builtin_bit_cast(float, (unsigned)((unsigned short)v) << 16);
}

// 4 bytes -> 4 bits (bit i = byte i nonzero)
__device__ __forceinline__ unsigned nib4(unsigned w4) {
    unsigned t = (w4 & 0x7f7f7f7fu) + 0x7f7f7f7fu;
    t |= w4;
    return (((t >> 7) & 0x01010101u) * 0x01020408u) >> 24;
}

// ---------------------------------------------------------------------------
// Kernel 1: mask detect (bool-1B vs int32) + bit-pack INVERTED (bit=KEEP),
// relayout to [(b*32+kt)*2048 + q] u64 words. Vectorized loads.
// ---------------------------------------------------------------------------
__global__ __launch_bounds__(256) void pack_mask_kernel(const void* __restrict__ mask,
                                                        unsigned* __restrict__ bits) {
    __shared__ int isBool;
    if (threadIdx.x == 0) isBool = 0;
    __syncthreads();
    const unsigned char* bytes = (const unsigned char*)mask;
    if (threadIdx.x < 64) {
        if (bytes[threadIdx.x * 4 + 1] | bytes[threadIdx.x * 4 + 2] | bytes[threadIdx.x * 4 + 3])
            isBool = 1;
    }
    __syncthreads();
    int t = blockIdx.x * 256 + threadIdx.x;          // 0..524287
    int half = t & 1, q = (t >> 1) & 2047, kt = (t >> 12) & 31, b = t >> 17;
    size_t src = ((size_t)(b * 2048 + q)) * 2048 + kt * 64 + half * 32;  // element idx
    unsigned v = 0;
    if (isBool) {
        const u32x4* p = (const u32x4*)(bytes + src);     // 32 bytes = 2 x 16B
        u32x4 w0 = p[0], w1 = p[1];
        v = nib4(w0[0]) | (nib4(w0[1]) << 4) | (nib4(w0[2]) << 8) | (nib4(w0[3]) << 12) |
            (nib4(w1[0]) << 16) | (nib4(w1[1]) << 20) | (nib4(w1[2]) << 24) | (nib4(w1[3]) << 28);
    } else {
        const u32x4* p = (const u32x4*)((const int*)mask + src);  // 32 ints = 8 x 16B
        #pragma unroll
        for (int j = 0; j < 8; ++j) {
            u32x4 wv = p[j];
            v |= ((wv[0] ? 1u : 0u) | (wv[1] ? 2u : 0u) | (wv[2] ? 4u : 0u) | (wv[3] ? 8u : 0u)) << (j * 4);
        }
    }
    bits[(((size_t)(b * 32 + kt)) * 2048 + q) * 2 + half] = ~v;   // KEEP bits
}

// ---------------------------------------------------------------------------
// Kernel 2: QKV projection. grid=(M/64, N/64, 3), x over M (round-11 version).
// Q out: [b][h][s][dk] bf16 (scaled log2e/8).
// K out: fragment-major K'[(b,h)][kt][ks][hi][key]x8 (16B units).
// V out: fragment-major V'[(b,h)][kt][kb][hi][dv]x8 (16B units).
// ---------------------------------------------------------------------------
__global__ __launch_bounds__(256) void proj_kernel(
    const float* __restrict__ inQ, const float* __restrict__ inK, const float* __restrict__ inV,
    const float* __restrict__ wq, const float* __restrict__ wk, const float* __restrict__ wv,
    short* __restrict__ Qp, short* __restrict__ Kp, short* __restrict__ Vp) {
    __shared__ short As[64 * 64];
    __shared__ short Bs[64 * 64];
    const int z = blockIdx.z;
    const float* A = (z == 0) ? inQ : ((z == 1) ? inK : inV);
    const float* W = (z == 0) ? wq : ((z == 1) ? wk : wv);
    short* O = (z == 0) ? Qp : ((z == 1) ? Kp : Vp);
    const float scale = (z == 0) ? 0.125f * 1.44269504f : 1.0f;   // log2e folded into Q
    const int bm = blockIdx.x * 64, bn = blockIdx.y * 64;
    const int tid = threadIdx.x, lane = tid & 63, wv_ = tid >> 6;
    const int wm = (wv_ >> 1) * 32, wn = (wv_ & 1) * 32;
    f32x4 acc[2][2] = {};

    for (int k0 = 0; k0 < 512; k0 += 64) {
        __syncthreads();
        #pragma unroll
        for (int it = 0; it < 4; ++it) {
            int g = tid + it * 256;
            int r = g >> 4, c4 = (g & 15) * 4;
            f32x4 v = *(const f32x4*)(A + (size_t)(bm + r) * 512 + k0 + c4);
            u32x2 u = { pk2(v.x, v.y), pk2(v.z, v.w) };
            *(u32x2*)((char*)As + r * 128 + ((c4 * 2) ^ ((r & 7) << 4))) = u;
        }
        #pragma unroll
        for (int it = 0; it < 2; ++it) {
            int g = tid + it * 256;
            int kp = g >> 4, n4 = (g & 15) * 4;
            const float* wrow = W + (size_t)(k0 + 2 * kp) * 512 + bn + n4;
            f32x4 va = *(const f32x4*)(wrow);
            f32x4 vb = *(const f32x4*)(wrow + 512);
            #pragma unroll
            for (int j = 0; j < 4; ++j) {
                int n = n4 + j;
                *(unsigned*)((char*)Bs + n * 128 + ((4 * kp) ^ ((n & 7) << 4))) = pk2(va[j], vb[j]);
            }
        }
        __syncthreads();
        #pragma unroll
        for (int kk = 0; kk < 2; ++kk) {
            short8_t af[2], bfr[2];
            #pragma unroll
            for (int rf = 0; rf < 2; ++rf) {
                int row = wm + rf * 16 + (lane & 15);
                af[rf] = *(const short8_t*)((const char*)As + row * 128 +
                          ((kk * 64 + ((lane >> 4) * 16)) ^ ((row & 7) << 4)));
            }
            #pragma unroll
            for (int cf = 0; cf < 2; ++cf) {
                int n = wn + cf * 16 + (lane & 15);
                bfr[cf] = *(const short8_t*)((const char*)Bs + n * 128 +
                           ((kk * 64 + ((lane >> 4) * 16)) ^ ((n & 7) << 4)));
            }
            __builtin_amdgcn_s_setprio(1);
            #pragma unroll
            for (int rf = 0; rf < 2; ++rf)
                #pragma unroll
                for (int cf = 0; cf < 2; ++cf)
                    acc[rf][cf] = __builtin_amdgcn_mfma_f32_16x16x32_bf16(af[rf], bfr[cf], acc[rf][cf], 0, 0, 0);
            __builtin_amdgcn_s_setprio(0);
        }
    }

    if (z == 0) {
        // Q: direct [b][h][s][dk]
        #pragma unroll
        for (int rf = 0; rf < 2; ++rf)
            #pragma unroll
            for (int cf = 0; cf < 2; ++cf)
                #pragma unroll
                for (int r = 0; r < 4; ++r) {
                    int row = bm + wm + rf * 16 + (lane >> 4) * 4 + r;
                    int col = bn + wn + cf * 16 + (lane & 15);
                    size_t idx = ((((size_t)(row >> 11)) * 8 + (col >> 6)) * 2048 + (row & 2047)) * 64 + (col & 63);
                    O[idx] = f2bf(acc[rf][cf][r] * scale);
                }
    } else {
        // K/V: stage to LDS (V transposed), then coalesced fragment-major stores.
        const int bb = bm >> 11, kt = (bm & 2047) >> 6, hh = bn >> 6;
        const size_t base = ((size_t)(bb * 8 + hh)) * 131072 + (size_t)kt * 4096;
        __syncthreads();   // As free (all waves past final mfma)
        if (z == 1) {
            #pragma unroll
            for (int rf = 0; rf < 2; ++rf)
                #pragma unroll
                for (int cf = 0; cf < 2; ++cf)
                    #pragma unroll
                    for (int r = 0; r < 4; ++r) {
                        int key = wm + rf * 16 + (lane >> 4) * 4 + r;
                        int dk = wn + cf * 16 + (lane & 15);
                        *(short*)((char*)As + key * 128 + ((dk * 2) ^ ((key & 7) << 4))) = f2bf(acc[rf][cf][r]);
                    }
        } else {
            #pragma unroll
            for (int rf = 0; rf < 2; ++rf)
                #pragma unroll
                for (int cf = 0; cf < 2; ++cf)
                    #pragma unroll
                    for (int r = 0; r < 4; ++r) {
                        int key = wm + rf * 16 + (lane >> 4) * 4 + r;
                        int dv = wn + cf * 16 + (lane & 15);
                        *(short*)((char*)As + dv * 128 + ((key * 2) ^ ((dv & 7) << 4))) = f2bf(acc[rf][cf][r]);
                    }
        }
        __syncthreads();
        // unit u: [ks|kb](2b) hi(1b) [key|dv](6b); 16B per unit, contiguous out.
        #pragma unroll
        for (int it = 0; it < 2; ++it) {
            int u = tid + it * 256;
            int blk = u >> 7, h2 = (u >> 6) & 1, rr = u & 63;
            short8_t v8 = *(const short8_t*)((const char*)As + rr * 128 +
                           ((blk * 32 + h2 * 16) ^ ((rr & 7) << 4)));
            *(short8_t*)(O + base + (size_t)u * 8) = v8;
        }
    }
}

// ---------------------------------------------------------------------------
// Kernel 3: barrier-free-loop flash attention with in-block split-KV.
// Block = 32 q-rows; wave w handles K-tiles [8w, 8w+8); LDS l-weighted merge.
// grid=(64, 8, 4) = 2048 blocks = 8 blocks/CU.
// ---------------------------------------------------------------------------
__global__ __launch_bounds__(256, 4) void attn_kernel(
    const short* __restrict__ Qp, const short* __restrict__ Kf, const short* __restrict__ Vf,
    const unsigned long long* __restrict__ mbits64, short* __restrict__ ctx) {
    __shared__ short Pw_all[4][2048];    // per-wave normalized partial (16KB)
    __shared__ float l_lds[4][32];
    // XCD-clustered remap: flat%8 ~ XCD; each XCD owns 4 whole (b,h) groups.
    int flat = blockIdx.x + 64 * (blockIdx.y + 8 * blockIdx.z);   // 0..2047
    int x8 = flat & 7, s = flat >> 3;                             // s: 0..255
    int bh = x8 * 4 + (s >> 6);                                   // 0..31
    int qi = s & 63;                                              // 0..63
    const int b = bh >> 3, h = bh & 7;
    const int tid = threadIdx.x, lane = tid & 63, w = tid >> 6;
    const int hi = lane >> 5, r31 = lane & 31;
    const size_t hb = ((size_t)bh) * 131072;
    const int qw = qi * 32;
    const int q_lane = qw + r31;
    const int t_beg = w * 8, t_end = t_beg + 8;

    short8_t qf[4];
    #pragma unroll
    for (int ks = 0; ks < 4; ++ks)
        qf[ks] = *(const short8_t*)(Qp + hb + (size_t)q_lane * 64 + ks * 16 + hi * 8);

    const short* Kb_ = Kf + hb + hi * 512 + r31 * 8;
    const short* Vb_ = Vf + hb + hi * 512 + r31 * 8;
    const unsigned long long* mrow = mbits64 + (size_t)b * 65536 + q_lane;

    f32x16 o0 = {}, o1 = {};
    float l_run = 0.f;

    for (int kt = t_beg; kt < t_end; ++kt) {
        const short* kp = Kb_ + (size_t)kt * 4096;
        unsigned long long wmx = mrow[(size_t)kt * 2048] >> (hi * 4);
        unsigned kl = (unsigned)wmx, kh = (unsigned)(wmx >> 32);

        // QK^T (log2 domain via Q scale)
        f32x16 s0 = {}, s1 = {};
        __builtin_amdgcn_s_setprio(1);
        #pragma unroll
        for (int ks = 0; ks < 4; ++ks) {
            short8_t kf0 = *(const short8_t*)(kp + ks * 1024);
            short8_t kf1 = *(const short8_t*)(kp + ks * 1024 + 256);
            s0 = __builtin_amdgcn_mfma_f32_32x32x16_bf16(kf0, qf[ks], s0, 0, 0, 0);
            s1 = __builtin_amdgcn_mfma_f32_32x32x16_bf16(kf1, qf[ks], s1, 0, 0, 0);
        }
        __builtin_amdgcn_s_setprio(0);

        // p = exp2(s) & keep, in-place; 4-way sum trees
        float r4[4] = { 0.f, 0.f, 0.f, 0.f };
        #pragma unroll
        for (int reg = 0; reg < 16; ++reg) {
            const int pos = (reg >> 2) * 8 + (reg & 3);
            float e0 = __builtin_amdgcn_exp2f(s0[reg]);
            float e1 = __builtin_amdgcn_exp2f(s1[reg]);
            unsigned k0b = (unsigned)__builtin_amdgcn_sbfe((int)kl, pos, 1);
            unsigned k1b = (unsigned)__builtin_amdgcn_sbfe((int)kh, pos, 1);
            float v0 = __builtin_bit_cast(float, __builtin_bit_cast(unsigned, e0) & k0b);
            float v1 = __builtin_bit_cast(float, __builtin_bit_cast(unsigned, e1) & k1b);
            s0[reg] = v0; s1[reg] = v1;
            r4[reg & 3] += v0 + v1;
        }
        float rs = (r4[0] + r4[1]) + (r4[2] + r4[3]);
        rs += __shfl_xor(rs, 32, 64);
        l_run += rs;

        // PV: O^T += V^T . P^T
        const short* vp = Vb_ + (size_t)kt * 4096;
        #pragma unroll
        for (int kb = 0; kb < 4; ++kb) {
            const int e = (kb & 1) * 8;
            unsigned c0 = (kb < 2) ? pk2(s0[e + 0], s0[e + 1]) : pk2(s1[e + 0], s1[e + 1]);
            unsigned c1 = (kb < 2) ? pk2(s0[e + 2], s0[e + 3]) : pk2(s1[e + 2], s1[e + 3]);
            unsigned c2 = (kb < 2) ? pk2(s0[e + 4], s0[e + 5]) : pk2(s1[e + 4], s1[e + 5]);
            unsigned c3 = (kb < 2) ? pk2(s0[e + 6], s0[e + 7]) : pk2(s1[e + 6], s1[e + 7]);
#if __has_builtin(__builtin_amdgcn_permlane32_swap)
            u32x2 r02 = __builtin_amdgcn_permlane32_swap(c0, c2, false, false);
            u32x2 r13 = __builtin_amdgcn_permlane32_swap(c1, c3, false, false);
            u32x4 bw = { r02[0], r13[0], r02[1], r13[1] };
#else
            unsigned x0 = __shfl_xor(c0, 32, 64), x1 = __shfl_xor(c1, 32, 64);
            unsigned x2 = __shfl_xor(c2, 32, 64), x3 = __shfl_xor(c3, 32, 64);
            unsigned w0 = hi ? x2 : c0, w1 = hi ? x3 : c1;
            unsigned w2 = hi ? c2 : x0, w3 = hi ? c3 : x1;
            u32x4 bw = { w0, w1, w2, w3 };
#endif
            short8_t pb = __builtin_bit_cast(short8_t, bw);
            short8_t vf0 = *(const short8_t*)(vp + kb * 1024);
            short8_t vf1 = *(const short8_t*)(vp + kb * 1024 + 256);
            __builtin_amdgcn_s_setprio(1);
            o0 = __builtin_amdgcn_mfma_f32_32x32x16_bf16(vf0, pb, o0, 0, 0, 0);
            o1 = __builtin_amdgcn_mfma_f32_32x32x16_bf16(vf1, pb, o1, 0, 0, 0);
            __builtin_amdgcn_s_setprio(0);
        }
    }

    // per-wave epilogue: normalize + transpose into LDS, post l
    float invl = 1.0f / fmaxf(l_run, 1e-37f);
    short* Pw = Pw_all[w];
    #pragma unroll
    for (int dvb = 0; dvb < 2; ++dvb)
        #pragma unroll
        for (int g = 0; g < 4; ++g) {
            short4_t v4;
            #pragma unroll
            for (int t = 0; t < 4; ++t) {
                float val = (dvb ? o1[g * 4 + t] : o0[g * 4 + t]) * invl;
                v4[t] = f2bf(val);
            }
            int dv0 = dvb * 32 + g * 8 + hi * 4;
            *(short4_t*)((char*)Pw + r31 * 128 + ((dv0 * 2) ^ ((r31 & 7) << 4))) = v4;
        }
    if (hi == 0) l_lds[w][r31] = l_run;
    __syncthreads();

    // block epilogue: l-weighted merge of the 4 wave partials -> ctx
    const int q = tid >> 3, j = tid & 7;
    float acc8[8] = {};
    float wsum = 0.f;
    #pragma unroll
    for (int ww = 0; ww < 4; ++ww) {
        float lw = l_lds[ww][q];
        wsum += lw;
        short8_t v8 = *(const short8_t*)((const char*)Pw_all[ww] + q * 128 + ((j * 16) ^ ((q & 7) << 4)));
        #pragma unroll
        for (int e = 0; e < 8; ++e)
            acc8[e] += bf2f(v8[e]) * lw;
    }
    float inv = 1.f / fmaxf(wsum, 1e-37f);
    u32x4 ov = { pk2(acc8[0] * inv, acc8[1] * inv), pk2(acc8[2] * inv, acc8[3] * inv),
                 pk2(acc8[4] * inv, acc8[5] * inv), pk2(acc8[6] * inv, acc8[7] * inv) };
    *(short8_t*)(ctx + ((size_t)(b * 2048 + qw + q)) * 512 + h * 64 + j * 8) =
        __builtin_bit_cast(short8_t, ov);
}

// ---------------------------------------------------------------------------
// Kernel 4: FC + residual, 128x64 tile, BK=64. grid=(64, 8).
// 4 waves, each owns 64x32 (wm=(w>>1)*64, wn=(w&1)*32).
// ---------------------------------------------------------------------------
__global__ __launch_bounds__(256) void fc_kernel(
    const short* __restrict__ ctx, const float* __restrict__ wfc,
    const float* __restrict__ inQ, float* __restrict__ xbuf) {
    __shared__ short As[128 * 64];   // 16KB
    __shared__ short Bs[64 * 64];    // 8KB
    const int bm = blockIdx.x * 128, bn = blockIdx.y * 64;
    const int tid = threadIdx.x, lane = tid & 63, wv_ = tid >> 6;
    const int wm = (wv_ >> 1) * 64, wn = (wv_ & 1) * 32;
    f32x4 acc[4][2] = {};

    for (int k0 = 0; k0 < 512; k0 += 64) {
        __syncthreads();
        // stage A (bf16 ctx): 128 rows x 64 k; short8 groups
        #pragma unroll
        for (int it = 0; it < 4; ++it) {
            int g = tid + it * 256;
            int r = g >> 3, c8 = (g & 7) * 8;
            short8_t v = *(const short8_t*)(ctx + (size_t)(bm + r) * 512 + k0 + c8);
            *(short8_t*)((char*)As + r * 128 + ((c8 * 2) ^ ((r & 7) << 4))) = v;
        }
        // stage B transposed: 64 k x 64 n
        #pragma unroll
        for (int it = 0; it < 2; ++it) {
            int g = tid + it * 256;
            int kp = g >> 4, n4 = (g & 15) * 4;
            const float* wrow = wfc + (size_t)(k0 + 2 * kp) * 512 + bn + n4;
            f32x4 va = *(const f32x4*)(wrow);
            f32x4 vb = *(const f32x4*)(wrow + 512);
            #pragma unroll
            for (int j = 0; j < 4; ++j) {
                int n = n4 + j;
                *(unsigned*)((char*)Bs + n * 128 + ((4 * kp) ^ ((n & 7) << 4))) = pk2(va[j], vb[j]);
            }
        }
        __syncthreads();
        #pragma unroll
        for (int kk = 0; kk < 2; ++kk) {
            short8_t af[4], bfr[2];
            #pragma unroll
            for (int rf = 0; rf < 4; ++rf) {
                int row = wm + rf * 16 + (lane & 15);
                af[rf] = *(const short8_t*)((const char*)As + row * 128 +
                          ((kk * 64 + ((lane >> 4) * 16)) ^ ((row & 7) << 4)));
            }
            #pragma unroll
            for (int cf = 0; cf < 2; ++cf) {
                int n = wn + cf * 16 + (lane & 15);
                bfr[cf] = *(const short8_t*)((const char*)Bs + n * 128 +
                           ((kk * 64 + ((lane >> 4) * 16)) ^ ((n & 7) << 4)));
            }
            __builtin_amdgcn_s_setprio(1);
            #pragma unroll
            for (int rf = 0; rf < 4; ++rf)
                #pragma unroll
                for (int cf = 0; cf < 2; ++cf)
                    acc[rf][cf] = __builtin_amdgcn_mfma_f32_16x16x32_bf16(af[rf], bfr[cf], acc[rf][cf], 0, 0, 0);
            __builtin_amdgcn_s_setprio(0);
        }
    }
    #pragma unroll
    for (int rf = 0; rf < 4; ++rf)
        #pragma unroll
        for (int cf = 0; cf < 2; ++cf)
            #pragma unroll
            for (int r = 0; r < 4; ++r) {
                int row = bm + wm + rf * 16 + (lane >> 4) * 4 + r;
                int col = bn + wn + cf * 16 + (lane & 15);
                size_t idx = (size_t)row * 512 + col;
                xbuf[idx] = acc[rf][cf][r] + inQ[idx];
            }
}

// ---------------------------------------------------------------------------
// Kernel 5: LayerNorm over D=512. Wave-per-row, no LDS, no barriers.
// grid=2048, 4 rows/block.
// ---------------------------------------------------------------------------
__global__ __launch_bounds__(256) void ln_kernel(
    const float* __restrict__ x, const float* __restrict__ gamma,
    const float* __restrict__ beta, float* __restrict__ out) {
    const int w = threadIdx.x >> 6, lane = threadIdx.x & 63;
    const int row = blockIdx.x * 4 + w;
    const f32x4* xr = (const f32x4*)(x + (size_t)row * 512);
    f32x4 a = xr[lane * 2], bb = xr[lane * 2 + 1];
    float s = (a.x + a.y) + (a.z + a.w) + (bb.x + bb.y) + (bb.z + bb.w);
    float sq = a.x * a.x + a.y * a.y + a.z * a.z + a.w * a.w +
               bb.x * bb.x + bb.y * bb.y + bb.z * bb.z + bb.w * bb.w;
    #pragma unroll
    for (int off = 32; off; off >>= 1) {
        s += __shfl_xor(s, off, 64);
        sq += __shfl_xor(sq, off, 64);
    }
    float mean = s * (1.f / 512.f);
    float var = sq * (1.f / 512.f) - mean * mean;
    float inv = rsqrtf(var + 1e-5f);
    const f32x4* gr = (const f32x4*)gamma;
    const f32x4* br = (const f32x4*)beta;
    f32x4 g0 = gr[lane * 2], g1 = gr[lane * 2 + 1];
    f32x4 b0 = br[lane * 2], b1 = br[lane * 2 + 1];
    f32x4 o0, o1;
    o0.x = (a.x - mean) * inv * g0.x + b0.x;
    o0.y = (a.y - mean) * inv * g0.y + b0.y;
    o0.z = (a.z - mean) * inv * g0.z + b0.z;
    o0.w = (a.w - mean) * inv * g0.w + b0.w;
    o1.x = (bb.x - mean) * inv * g1.x + b1.x;
    o1.y = (bb.y - mean) * inv * g1.y + b1.y;
    o1.z = (bb.z - mean) * inv * g1.z + b1.z;
    o1.w = (bb.w - mean) * inv * g1.w + b1.w;
    f32x4* orow = (f32x4*)(out + (size_t)row * 512);
    orow[lane * 2] = o0;
    orow[lane * 2 + 1] = o1;
}

// ---------------------------------------------------------------------------
extern "C" void kernel_launch(void* const* d_in, const int* in_sizes, int n_in,
                              void* d_out, int out_size, void* d_ws, size_t ws_size,
                              hipStream_t stream) {
    const float* inQ = (const float*)d_in[0];
    const float* inK = (const float*)d_in[1];
    const float* inV = (const float*)d_in[2];
    const void* mask = d_in[3];
    const float* wq = (const float*)d_in[4];
    const float* wk = (const float*)d_in[5];
    const float* wv = (const float*)d_in[6];
    const float* wfc = (const float*)d_in[7];
    const float* gamma = (const float*)d_in[8];
    const float* beta = (const float*)d_in[9];
    float* out = (float*)d_out;
    char* ws = (char*)d_ws;

    short* Qp = (short*)(ws);                          // 8 MB
    short* Kp = (short*)(ws + (size_t)(8 << 20));      // 8 MB, fragment-major
    short* Vp = (short*)(ws + (size_t)(16 << 20));     // 8 MB, fragment-major
    short* ctx = (short*)(ws + (size_t)(24 << 20));    // 8 MB
    unsigned* mbits = (unsigned*)(ws + (size_t)(32 << 20)); // 2 MB
    float* xbuf = (float*)(ws);                        // 16 MB, reuses Qp/Kp (dead after attn)

    pack_mask_kernel<<<2048, 256, 0, stream>>>(mask, mbits);
    proj_kernel<<<dim3(128, 8, 3), 256, 0, stream>>>(inQ, inK, inV, wq, wk, wv, Qp, Kp, Vp);
    attn_kernel<<<dim3(64, 8, 4), 256, 0, stream>>>(
        Qp, Kp, Vp, (const unsigned long long*)mbits, ctx);
    fc_kernel<<<dim3(64, 8), 256, 0, stream>>>(ctx, wfc, inQ, xbuf);
    ln_kernel<<<2048, 256, 0, stream>>>(xbuf, gamma, beta, out);
}

// Round 15
// 137.428 us; speedup vs baseline: 1.1554x; 1.0488x over previous
//
#include <hip/hip_runtime.h>

// FullAttention fused pipeline for MI355X (gfx950).
// B=4 S=2048 D=512 H=8 DK=DV=64.
// Round 15: restore round-11 exactly (measured best, 136.8 us). Round 14
// isolated fc-128x64 as a -7us regression (2 blocks/CU residency loss beats
// MFMA-density gain in the fp32-convert staging regime). Components at
// measured floors: attn 65us (3 structures), ln/pack at HBM roofline.

#define B_ 4
#define S_ 2048
#define D_ 512
#define H_ 8

typedef __attribute__((ext_vector_type(8))) short short8_t;
typedef __attribute__((ext_vector_type(4))) short short4_t;
typedef __attribute__((ext_vector_type(4))) float f32x4;
typedef __attribute__((ext_vector_type(16))) float f32x16;
typedef __attribute__((ext_vector_type(4))) unsigned u32x4;
typedef __attribute__((ext_vector_type(2))) unsigned u32x2;

__device__ __forceinline__ short f2bf(float f) {
    unsigned u = __builtin_bit_cast(unsigned, f);
    u += 0x7fff + ((u >> 16) & 1);   // RNE
    return (short)(u >> 16);
}

// pack two f32 -> two bf16 (truncation) via one v_perm_b32
__device__ __forceinline__ unsigned pk2(float a, float b) {
    return __builtin_amdgcn_perm(__builtin_bit_cast(unsigned, b),
                                 __builtin_bit_cast(unsigned, a), 0x07060302u);
}

__device__ __forceinline__ float bf2f(short v) {
    return __builtin_bit_cast(float, (unsigned)((unsigned short)v) << 16);
}

// 4 bytes -> 4 bits (bit i = byte i nonzero)
__device__ __forceinline__ unsigned nib4(unsigned w4) {
    unsigned t = (w4 & 0x7f7f7f7fu) + 0x7f7f7f7fu;
    t |= w4;
    return (((t >> 7) & 0x01010101u) * 0x01020408u) >> 24;
}

// ---------------------------------------------------------------------------
// Kernel 1: mask detect (bool-1B vs int32) + bit-pack INVERTED (bit=KEEP),
// relayout to [(b*32+kt)*2048 + q] u64 words. Vectorized loads.
// ---------------------------------------------------------------------------
__global__ __launch_bounds__(256) void pack_mask_kernel(const void* __restrict__ mask,
                                                        unsigned* __restrict__ bits) {
    __shared__ int isBool;
    if (threadIdx.x == 0) isBool = 0;
    __syncthreads();
    const unsigned char* bytes = (const unsigned char*)mask;
    if (threadIdx.x < 64) {
        if (bytes[threadIdx.x * 4 + 1] | bytes[threadIdx.x * 4 + 2] | bytes[threadIdx.x * 4 + 3])
            isBool = 1;
    }
    __syncthreads();
    int t = blockIdx.x * 256 + threadIdx.x;          // 0..524287
    int half = t & 1, q = (t >> 1) & 2047, kt = (t >> 12) & 31, b = t >> 17;
    size_t src = ((size_t)(b * 2048 + q)) * 2048 + kt * 64 + half * 32;  // element idx
    unsigned v = 0;
    if (isBool) {
        const u32x4* p = (const u32x4*)(bytes + src);     // 32 bytes = 2 x 16B
        u32x4 w0 = p[0], w1 = p[1];
        v = nib4(w0[0]) | (nib4(w0[1]) << 4) | (nib4(w0[2]) << 8) | (nib4(w0[3]) << 12) |
            (nib4(w1[0]) << 16) | (nib4(w1[1]) << 20) | (nib4(w1[2]) << 24) | (nib4(w1[3]) << 28);
    } else {
        const u32x4* p = (const u32x4*)((const int*)mask + src);  // 32 ints = 8 x 16B
        #pragma unroll
        for (int j = 0; j < 8; ++j) {
            u32x4 wv = p[j];
            v |= ((wv[0] ? 1u : 0u) | (wv[1] ? 2u : 0u) | (wv[2] ? 4u : 0u) | (wv[3] ? 8u : 0u)) << (j * 4);
        }
    }
    bits[(((size_t)(b * 32 + kt)) * 2048 + q) * 2 + half] = ~v;   // KEEP bits
}

// ---------------------------------------------------------------------------
// Kernel 2: QKV projection. grid=(M/64, N/64, 3), x over M.
// Q out: [b][h][s][dk] bf16 (scaled log2e/8).
// K out: fragment-major K'[(b,h)][kt][ks][hi][key]x8 (16B units).
// V out: fragment-major V'[(b,h)][kt][kb][hi][dv]x8 (16B units).
// ---------------------------------------------------------------------------
__global__ __launch_bounds__(256) void proj_kernel(
    const float* __restrict__ inQ, const float* __restrict__ inK, const float* __restrict__ inV,
    const float* __restrict__ wq, const float* __restrict__ wk, const float* __restrict__ wv,
    short* __restrict__ Qp, short* __restrict__ Kp, short* __restrict__ Vp) {
    __shared__ short As[64 * 64];
    __shared__ short Bs[64 * 64];
    const int z = blockIdx.z;
    const float* A = (z == 0) ? inQ : ((z == 1) ? inK : inV);
    const float* W = (z == 0) ? wq : ((z == 1) ? wk : wv);
    short* O = (z == 0) ? Qp : ((z == 1) ? Kp : Vp);
    const float scale = (z == 0) ? 0.125f * 1.44269504f : 1.0f;   // log2e folded into Q
    const int bm = blockIdx.x * 64, bn = blockIdx.y * 64;
    const int tid = threadIdx.x, lane = tid & 63, wv_ = tid >> 6;
    const int wm = (wv_ >> 1) * 32, wn = (wv_ & 1) * 32;
    f32x4 acc[2][2] = {};

    for (int k0 = 0; k0 < 512; k0 += 64) {
        __syncthreads();
        #pragma unroll
        for (int it = 0; it < 4; ++it) {
            int g = tid + it * 256;
            int r = g >> 4, c4 = (g & 15) * 4;
            f32x4 v = *(const f32x4*)(A + (size_t)(bm + r) * 512 + k0 + c4);
            u32x2 u = { pk2(v.x, v.y), pk2(v.z, v.w) };
            *(u32x2*)((char*)As + r * 128 + ((c4 * 2) ^ ((r & 7) << 4))) = u;
        }
        #pragma unroll
        for (int it = 0; it < 2; ++it) {
            int g = tid + it * 256;
            int kp = g >> 4, n4 = (g & 15) * 4;
            const float* wrow = W + (size_t)(k0 + 2 * kp) * 512 + bn + n4;
            f32x4 va = *(const f32x4*)(wrow);
            f32x4 vb = *(const f32x4*)(wrow + 512);
            #pragma unroll
            for (int j = 0; j < 4; ++j) {
                int n = n4 + j;
                *(unsigned*)((char*)Bs + n * 128 + ((4 * kp) ^ ((n & 7) << 4))) = pk2(va[j], vb[j]);
            }
        }
        __syncthreads();
        #pragma unroll
        for (int kk = 0; kk < 2; ++kk) {
            short8_t af[2], bfr[2];
            #pragma unroll
            for (int rf = 0; rf < 2; ++rf) {
                int row = wm + rf * 16 + (lane & 15);
                af[rf] = *(const short8_t*)((const char*)As + row * 128 +
                          ((kk * 64 + ((lane >> 4) * 16)) ^ ((row & 7) << 4)));
            }
            #pragma unroll
            for (int cf = 0; cf < 2; ++cf) {
                int n = wn + cf * 16 + (lane & 15);
                bfr[cf] = *(const short8_t*)((const char*)Bs + n * 128 +
                           ((kk * 64 + ((lane >> 4) * 16)) ^ ((n & 7) << 4)));
            }
            __builtin_amdgcn_s_setprio(1);
            #pragma unroll
            for (int rf = 0; rf < 2; ++rf)
                #pragma unroll
                for (int cf = 0; cf < 2; ++cf)
                    acc[rf][cf] = __builtin_amdgcn_mfma_f32_16x16x32_bf16(af[rf], bfr[cf], acc[rf][cf], 0, 0, 0);
            __builtin_amdgcn_s_setprio(0);
        }
    }

    if (z == 0) {
        // Q: direct [b][h][s][dk]
        #pragma unroll
        for (int rf = 0; rf < 2; ++rf)
            #pragma unroll
            for (int cf = 0; cf < 2; ++cf)
                #pragma unroll
                for (int r = 0; r < 4; ++r) {
                    int row = bm + wm + rf * 16 + (lane >> 4) * 4 + r;
                    int col = bn + wn + cf * 16 + (lane & 15);
                    size_t idx = ((((size_t)(row >> 11)) * 8 + (col >> 6)) * 2048 + (row & 2047)) * 64 + (col & 63);
                    O[idx] = f2bf(acc[rf][cf][r] * scale);
                }
    } else {
        // K/V: stage to LDS (V transposed), then coalesced fragment-major stores.
        const int bb = bm >> 11, kt = (bm & 2047) >> 6, hh = bn >> 6;
        const size_t base = ((size_t)(bb * 8 + hh)) * 131072 + (size_t)kt * 4096;
        __syncthreads();   // As free (all waves past final mfma)
        if (z == 1) {
            #pragma unroll
            for (int rf = 0; rf < 2; ++rf)
                #pragma unroll
                for (int cf = 0; cf < 2; ++cf)
                    #pragma unroll
                    for (int r = 0; r < 4; ++r) {
                        int key = wm + rf * 16 + (lane >> 4) * 4 + r;
                        int dk = wn + cf * 16 + (lane & 15);
                        *(short*)((char*)As + key * 128 + ((dk * 2) ^ ((key & 7) << 4))) = f2bf(acc[rf][cf][r]);
                    }
        } else {
            #pragma unroll
            for (int rf = 0; rf < 2; ++rf)
                #pragma unroll
                for (int cf = 0; cf < 2; ++cf)
                    #pragma unroll
                    for (int r = 0; r < 4; ++r) {
                        int key = wm + rf * 16 + (lane >> 4) * 4 + r;
                        int dv = wn + cf * 16 + (lane & 15);
                        *(short*)((char*)As + dv * 128 + ((key * 2) ^ ((dv & 7) << 4))) = f2bf(acc[rf][cf][r]);
                    }
        }
        __syncthreads();
        // unit u: [ks|kb](2b) hi(1b) [key|dv](6b); 16B per unit, contiguous out.
        #pragma unroll
        for (int it = 0; it < 2; ++it) {
            int u = tid + it * 256;
            int blk = u >> 7, h2 = (u >> 6) & 1, rr = u & 63;
            short8_t v8 = *(const short8_t*)((const char*)As + rr * 128 +
                           ((blk * 32 + h2 * 16) ^ ((rr & 7) << 4)));
            *(short8_t*)(O + base + (size_t)u * 8) = v8;
        }
    }
}

// ---------------------------------------------------------------------------
// Kernel 3: barrier-free-loop flash attention with in-block split-KV.
// Block = 32 q-rows; wave w handles K-tiles [8w, 8w+8); LDS l-weighted merge.
// grid=(64, 8, 4) = 2048 blocks = 8 blocks/CU.
// ---------------------------------------------------------------------------
__global__ __launch_bounds__(256, 4) void attn_kernel(
    const short* __restrict__ Qp, const short* __restrict__ Kf, const short* __restrict__ Vf,
    const unsigned long long* __restrict__ mbits64, short* __restrict__ ctx) {
    __shared__ short Pw_all[4][2048];    // per-wave normalized partial (16KB)
    __shared__ float l_lds[4][32];
    // XCD-clustered remap: flat%8 ~ XCD; each XCD owns 4 whole (b,h) groups.
    int flat = blockIdx.x + 64 * (blockIdx.y + 8 * blockIdx.z);   // 0..2047
    int x8 = flat & 7, s = flat >> 3;                             // s: 0..255
    int bh = x8 * 4 + (s >> 6);                                   // 0..31
    int qi = s & 63;                                              // 0..63
    const int b = bh >> 3, h = bh & 7;
    const int tid = threadIdx.x, lane = tid & 63, w = tid >> 6;
    const int hi = lane >> 5, r31 = lane & 31;
    const size_t hb = ((size_t)bh) * 131072;
    const int qw = qi * 32;
    const int q_lane = qw + r31;
    const int t_beg = w * 8, t_end = t_beg + 8;

    short8_t qf[4];
    #pragma unroll
    for (int ks = 0; ks < 4; ++ks)
        qf[ks] = *(const short8_t*)(Qp + hb + (size_t)q_lane * 64 + ks * 16 + hi * 8);

    const short* Kb_ = Kf + hb + hi * 512 + r31 * 8;
    const short* Vb_ = Vf + hb + hi * 512 + r31 * 8;
    const unsigned long long* mrow = mbits64 + (size_t)b * 65536 + q_lane;

    f32x16 o0 = {}, o1 = {};
    float l_run = 0.f;

    for (int kt = t_beg; kt < t_end; ++kt) {
        const short* kp = Kb_ + (size_t)kt * 4096;
        unsigned long long wmx = mrow[(size_t)kt * 2048] >> (hi * 4);
        unsigned kl = (unsigned)wmx, kh = (unsigned)(wmx >> 32);

        // QK^T (log2 domain via Q scale)
        f32x16 s0 = {}, s1 = {};
        __builtin_amdgcn_s_setprio(1);
        #pragma unroll
        for (int ks = 0; ks < 4; ++ks) {
            short8_t kf0 = *(const short8_t*)(kp + ks * 1024);
            short8_t kf1 = *(const short8_t*)(kp + ks * 1024 + 256);
            s0 = __builtin_amdgcn_mfma_f32_32x32x16_bf16(kf0, qf[ks], s0, 0, 0, 0);
            s1 = __builtin_amdgcn_mfma_f32_32x32x16_bf16(kf1, qf[ks], s1, 0, 0, 0);
        }
        __builtin_amdgcn_s_setprio(0);

        // p = exp2(s) & keep, in-place; 4-way sum trees
        float r4[4] = { 0.f, 0.f, 0.f, 0.f };
        #pragma unroll
        for (int reg = 0; reg < 16; ++reg) {
            const int pos = (reg >> 2) * 8 + (reg & 3);
            float e0 = __builtin_amdgcn_exp2f(s0[reg]);
            float e1 = __builtin_amdgcn_exp2f(s1[reg]);
            unsigned k0b = (unsigned)__builtin_amdgcn_sbfe((int)kl, pos, 1);
            unsigned k1b = (unsigned)__builtin_amdgcn_sbfe((int)kh, pos, 1);
            float v0 = __builtin_bit_cast(float, __builtin_bit_cast(unsigned, e0) & k0b);
            float v1 = __builtin_bit_cast(float, __builtin_bit_cast(unsigned, e1) & k1b);
            s0[reg] = v0; s1[reg] = v1;
            r4[reg & 3] += v0 + v1;
        }
        float rs = (r4[0] + r4[1]) + (r4[2] + r4[3]);
        rs += __shfl_xor(rs, 32, 64);
        l_run += rs;

        // PV: O^T += V^T . P^T
        const short* vp = Vb_ + (size_t)kt * 4096;
        #pragma unroll
        for (int kb = 0; kb < 4; ++kb) {
            const int e = (kb & 1) * 8;
            unsigned c0 = (kb < 2) ? pk2(s0[e + 0], s0[e + 1]) : pk2(s1[e + 0], s1[e + 1]);
            unsigned c1 = (kb < 2) ? pk2(s0[e + 2], s0[e + 3]) : pk2(s1[e + 2], s1[e + 3]);
            unsigned c2 = (kb < 2) ? pk2(s0[e + 4], s0[e + 5]) : pk2(s1[e + 4], s1[e + 5]);
            unsigned c3 = (kb < 2) ? pk2(s0[e + 6], s0[e + 7]) : pk2(s1[e + 6], s1[e + 7]);
#if __has_builtin(__builtin_amdgcn_permlane32_swap)
            u32x2 r02 = __builtin_amdgcn_permlane32_swap(c0, c2, false, false);
            u32x2 r13 = __builtin_amdgcn_permlane32_swap(c1, c3, false, false);
            u32x4 bw = { r02[0], r13[0], r02[1], r13[1] };
#else
            unsigned x0 = __shfl_xor(c0, 32, 64), x1 = __shfl_xor(c1, 32, 64);
            unsigned x2 = __shfl_xor(c2, 32, 64), x3 = __shfl_xor(c3, 32, 64);
            unsigned w0 = hi ? x2 : c0, w1 = hi ? x3 : c1;
            unsigned w2 = hi ? c2 : x0, w3 = hi ? c3 : x1;
            u32x4 bw = { w0, w1, w2, w3 };
#endif
            short8_t pb = __builtin_bit_cast(short8_t, bw);
            short8_t vf0 = *(const short8_t*)(vp + kb * 1024);
            short8_t vf1 = *(const short8_t*)(vp + kb * 1024 + 256);
            __builtin_amdgcn_s_setprio(1);
            o0 = __builtin_amdgcn_mfma_f32_32x32x16_bf16(vf0, pb, o0, 0, 0, 0);
            o1 = __builtin_amdgcn_mfma_f32_32x32x16_bf16(vf1, pb, o1, 0, 0, 0);
            __builtin_amdgcn_s_setprio(0);
        }
    }

    // per-wave epilogue: normalize + transpose into LDS, post l
    float invl = 1.0f / fmaxf(l_run, 1e-37f);
    short* Pw = Pw_all[w];
    #pragma unroll
    for (int dvb = 0; dvb < 2; ++dvb)
        #pragma unroll
        for (int g = 0; g < 4; ++g) {
            short4_t v4;
            #pragma unroll
            for (int t = 0; t < 4; ++t) {
                float val = (dvb ? o1[g * 4 + t] : o0[g * 4 + t]) * invl;
                v4[t] = f2bf(val);
            }
            int dv0 = dvb * 32 + g * 8 + hi * 4;
            *(short4_t*)((char*)Pw + r31 * 128 + ((dv0 * 2) ^ ((r31 & 7) << 4))) = v4;
        }
    if (hi == 0) l_lds[w][r31] = l_run;
    __syncthreads();

    // block epilogue: l-weighted merge of the 4 wave partials -> ctx
    const int q = tid >> 3, j = tid & 7;
    float acc8[8] = {};
    float wsum = 0.f;
    #pragma unroll
    for (int ww = 0; ww < 4; ++ww) {
        float lw = l_lds[ww][q];
        wsum += lw;
        short8_t v8 = *(const short8_t*)((const char*)Pw_all[ww] + q * 128 + ((j * 16) ^ ((q & 7) << 4)));
        #pragma unroll
        for (int e = 0; e < 8; ++e)
            acc8[e] += bf2f(v8[e]) * lw;
    }
    float inv = 1.f / fmaxf(wsum, 1e-37f);
    u32x4 ov = { pk2(acc8[0] * inv, acc8[1] * inv), pk2(acc8[2] * inv, acc8[3] * inv),
                 pk2(acc8[4] * inv, acc8[5] * inv), pk2(acc8[6] * inv, acc8[7] * inv) };
    *(short8_t*)(ctx + ((size_t)(b * 2048 + qw + q)) * 512 + h * 64 + j * 8) =
        __builtin_bit_cast(short8_t, ov);
}

// ---------------------------------------------------------------------------
// Kernel 4: FC + residual. grid=(M/64, N/64), x over M. (round-11 64x64 tile)
// ---------------------------------------------------------------------------
__global__ __launch_bounds__(256) void fc_kernel(
    const short* __restrict__ ctx, const float* __restrict__ wfc,
    const float* __restrict__ inQ, float* __restrict__ xbuf) {
    __shared__ short As[64 * 64];
    __shared__ short Bs[64 * 64];
    const int bm = blockIdx.x * 64, bn = blockIdx.y * 64;
    const int tid = threadIdx.x, lane = tid & 63, wv_ = tid >> 6;
    const int wm = (wv_ >> 1) * 32, wn = (wv_ & 1) * 32;
    f32x4 acc[2][2] = {};

    for (int k0 = 0; k0 < 512; k0 += 64) {
        __syncthreads();
        #pragma unroll
        for (int it = 0; it < 2; ++it) {
            int g = tid + it * 256;
            int r = g >> 3, c8 = (g & 7) * 8;
            short8_t v = *(const short8_t*)(ctx + (size_t)(bm + r) * 512 + k0 + c8);
            *(short8_t*)((char*)As + r * 128 + ((c8 * 2) ^ ((r & 7) << 4))) = v;
        }
        #pragma unroll
        for (int it = 0; it < 2; ++it) {
            int g = tid + it * 256;
            int kp = g >> 4, n4 = (g & 15) * 4;
            const float* wrow = wfc + (size_t)(k0 + 2 * kp) * 512 + bn + n4;
            f32x4 va = *(const f32x4*)(wrow);
            f32x4 vb = *(const f32x4*)(wrow + 512);
            #pragma unroll
            for (int j = 0; j < 4; ++j) {
                int n = n4 + j;
                *(unsigned*)((char*)Bs + n * 128 + ((4 * kp) ^ ((n & 7) << 4))) = pk2(va[j], vb[j]);
            }
        }
        __syncthreads();
        #pragma unroll
        for (int kk = 0; kk < 2; ++kk) {
            short8_t af[2], bfr[2];
            #pragma unroll
            for (int rf = 0; rf < 2; ++rf) {
                int row = wm + rf * 16 + (lane & 15);
                af[rf] = *(const short8_t*)((const char*)As + row * 128 +
                          ((kk * 64 + ((lane >> 4) * 16)) ^ ((row & 7) << 4)));
            }
            #pragma unroll
            for (int cf = 0; cf < 2; ++cf) {
                int n = wn + cf * 16 + (lane & 15);
                bfr[cf] = *(const short8_t*)((const char*)Bs + n * 128 +
                           ((kk * 64 + ((lane >> 4) * 16)) ^ ((n & 7) << 4)));
            }
            __builtin_amdgcn_s_setprio(1);
            #pragma unroll
            for (int rf = 0; rf < 2; ++rf)
                #pragma unroll
                for (int cf = 0; cf < 2; ++cf)
                    acc[rf][cf] = __builtin_amdgcn_mfma_f32_16x16x32_bf16(af[rf], bfr[cf], acc[rf][cf], 0, 0, 0);
            __builtin_amdgcn_s_setprio(0);
        }
    }
    #pragma unroll
    for (int rf = 0; rf < 2; ++rf)
        #pragma unroll
        for (int cf = 0; cf < 2; ++cf)
            #pragma unroll
            for (int r = 0; r < 4; ++r) {
                int row = bm + wm + rf * 16 + (lane >> 4) * 4 + r;
                int col = bn + wn + cf * 16 + (lane & 15);
                size_t idx = (size_t)row * 512 + col;
                xbuf[idx] = acc[rf][cf][r] + inQ[idx];
            }
}

// ---------------------------------------------------------------------------
// Kernel 5: LayerNorm over D=512. Wave-per-row, no LDS, no barriers.
// grid=2048, 4 rows/block.
// ---------------------------------------------------------------------------
__global__ __launch_bounds__(256) void ln_kernel(
    const float* __restrict__ x, const float* __restrict__ gamma,
    const float* __restrict__ beta, float* __restrict__ out) {
    const int w = threadIdx.x >> 6, lane = threadIdx.x & 63;
    const int row = blockIdx.x * 4 + w;
    const f32x4* xr = (const f32x4*)(x + (size_t)row * 512);
    f32x4 a = xr[lane * 2], bb = xr[lane * 2 + 1];
    float s = (a.x + a.y) + (a.z + a.w) + (bb.x + bb.y) + (bb.z + bb.w);
    float sq = a.x * a.x + a.y * a.y + a.z * a.z + a.w * a.w +
               bb.x * bb.x + bb.y * bb.y + bb.z * bb.z + bb.w * bb.w;
    #pragma unroll
    for (int off = 32; off; off >>= 1) {
        s += __shfl_xor(s, off, 64);
        sq += __shfl_xor(sq, off, 64);
    }
    float mean = s * (1.f / 512.f);
    float var = sq * (1.f / 512.f) - mean * mean;
    float inv = rsqrtf(var + 1e-5f);
    const f32x4* gr = (const f32x4*)gamma;
    const f32x4* br = (const f32x4*)beta;
    f32x4 g0 = gr[lane * 2], g1 = gr[lane * 2 + 1];
    f32x4 b0 = br[lane * 2], b1 = br[lane * 2 + 1];
    f32x4 o0, o1;
    o0.x = (a.x - mean) * inv * g0.x + b0.x;
    o0.y = (a.y - mean) * inv * g0.y + b0.y;
    o0.z = (a.z - mean) * inv * g0.z + b0.z;
    o0.w = (a.w - mean) * inv * g0.w + b0.w;
    o1.x = (bb.x - mean) * inv * g1.x + b1.x;
    o1.y = (bb.y - mean) * inv * g1.y + b1.y;
    o1.z = (bb.z - mean) * inv * g1.z + b1.z;
    o1.w = (bb.w - mean) * inv * g1.w + b1.w;
    f32x4* orow = (f32x4*)(out + (size_t)row * 512);
    orow[lane * 2] = o0;
    orow[lane * 2 + 1] = o1;
}

// ---------------------------------------------------------------------------
extern "C" void kernel_launch(void* const* d_in, const int* in_sizes, int n_in,
                              void* d_out, int out_size, void* d_ws, size_t ws_size,
                              hipStream_t stream) {
    const float* inQ = (const float*)d_in[0];
    const float* inK = (const float*)d_in[1];
    const float* inV = (const float*)d_in[2];
    const void* mask = d_in[3];
    const float* wq = (const float*)d_in[4];
    const float* wk = (const float*)d_in[5];
    const float* wv = (const float*)d_in[6];
    const float* wfc = (const float*)d_in[7];
    const float* gamma = (const float*)d_in[8];
    const float* beta = (const float*)d_in[9];
    float* out = (float*)d_out;
    char* ws = (char*)d_ws;

    short* Qp = (short*)(ws);                          // 8 MB
    short* Kp = (short*)(ws + (size_t)(8 << 20));      // 8 MB, fragment-major
    short* Vp = (short*)(ws + (size_t)(16 << 20));     // 8 MB, fragment-major
    short* ctx = (short*)(ws + (size_t)(24 << 20));    // 8 MB
    unsigned* mbits = (unsigned*)(ws + (size_t)(32 << 20)); // 2 MB
    float* xbuf = (float*)(ws);                        // 16 MB, reuses Qp/Kp (dead after attn)

    pack_mask_kernel<<<2048, 256, 0, stream>>>(mask, mbits);
    proj_kernel<<<dim3(128, 8, 3), 256, 0, stream>>>(inQ, inK, inV, wq, wk, wv, Qp, Kp, Vp);
    attn_kernel<<<dim3(64, 8, 4), 256, 0, stream>>>(
        Qp, Kp, Vp, (const unsigned long long*)mbits, ctx);
    fc_kernel<<<dim3(128, 8, 1), 256, 0, stream>>>(ctx, wfc, inQ, xbuf);
    ln_kernel<<<2048, 256, 0, stream>>>(xbuf, gamma, beta, out);
}

// Round 18
// 126.788 us; speedup vs baseline: 1.2524x; 1.0839x over previous
//
#include <hip/hip_runtime.h>

// FullAttention fused pipeline for MI355X (gfx950).
// B=4 S=2048 D=512 H=8 DK=DV=64.
// Round 18: resubmit of round 16/17 (two infra transport failures; kernel
// never ran). Weights pre-converted+pre-transposed once (wprep -> bf16 [n][k],
// 2MB in ws). proj/fc B-staging becomes short8 load + short8 LDS store
// (removes per-block fp32 loads, pk2s, and 4B scatter-store bank conflicts).
// Everything else byte-identical to round 15 (137.4us best).

#define B_ 4
#define S_ 2048
#define D_ 512
#define H_ 8

typedef __attribute__((ext_vector_type(8))) short short8_t;
typedef __attribute__((ext_vector_type(4))) short short4_t;
typedef __attribute__((ext_vector_type(4))) float f32x4;
typedef __attribute__((ext_vector_type(16))) float f32x16;
typedef __attribute__((ext_vector_type(4))) unsigned u32x4;
typedef __attribute__((ext_vector_type(2))) unsigned u32x2;

__device__ __forceinline__ short f2bf(float f) {
    unsigned u = __builtin_bit_cast(unsigned, f);
    u += 0x7fff + ((u >> 16) & 1);   // RNE
    return (short)(u >> 16);
}

// pack two f32 -> two bf16 (truncation) via one v_perm_b32
__device__ __forceinline__ unsigned pk2(float a, float b) {
    return __builtin_amdgcn_perm(__builtin_bit_cast(unsigned, b),
                                 __builtin_bit_cast(unsigned, a), 0x07060302u);
}

__device__ __forceinline__ float bf2f(short v) {
    return __builtin_bit_cast(float, (unsigned)((unsigned short)v) << 16);
}

// 4 bytes -> 4 bits (bit i = byte i nonzero)
__device__ __forceinline__ unsigned nib4(unsigned w4) {
    unsigned t = (w4 & 0x7f7f7f7fu) + 0x7f7f7f7fu;
    t |= w4;
    return (((t >> 7) & 0x01010101u) * 0x01020408u) >> 24;
}

// ---------------------------------------------------------------------------
// Kernel 0: weight prep. 4 matrices (wq,wk,wv,wfc) fp32 [k][n] -> bf16 [n][k].
// grid=(8,8,4): (k-tile, n-tile, matrix). Stage+de-swizzle via LDS.
// ---------------------------------------------------------------------------
__global__ __launch_bounds__(256) void wprep_kernel(
    const float* __restrict__ wq, const float* __restrict__ wk,
    const float* __restrict__ wv, const float* __restrict__ wfc,
    short* __restrict__ wt) {
    __shared__ short Bs[64 * 64];
    const int k0 = blockIdx.x * 64, n0 = blockIdx.y * 64, m = blockIdx.z;
    const float* W = (m == 0) ? wq : ((m == 1) ? wk : ((m == 2) ? wv : wfc));
    const int tid = threadIdx.x;
    #pragma unroll
    for (int it = 0; it < 2; ++it) {
        int g = tid + it * 256;
        int kp = g >> 4, n4 = (g & 15) * 4;
        const float* wrow = W + (size_t)(k0 + 2 * kp) * 512 + n0 + n4;
        f32x4 va = *(const f32x4*)(wrow);
        f32x4 vb = *(const f32x4*)(wrow + 512);
        #pragma unroll
        for (int j = 0; j < 4; ++j) {
            int n = n4 + j;
            *(unsigned*)((char*)Bs + n * 128 + ((4 * kp) ^ ((n & 7) << 4))) = pk2(va[j], vb[j]);
        }
    }
    __syncthreads();
    #pragma unroll
    for (int it = 0; it < 2; ++it) {
        int g = tid + it * 256;                 // 512 groups of 8
        int n = g >> 3, c8 = (g & 7) * 8;
        short8_t v = *(const short8_t*)((const char*)Bs + n * 128 + ((c8 * 2) ^ ((n & 7) << 4)));
        *(short8_t*)(wt + ((size_t)m * 512 + n0 + n) * 512 + k0 + c8) = v;
    }
}

// ---------------------------------------------------------------------------
// Kernel 1: mask detect (bool-1B vs int32) + bit-pack INVERTED (bit=KEEP),
// relayout to [(b*32+kt)*2048 + q] u64 words. Vectorized loads.
// ---------------------------------------------------------------------------
__global__ __launch_bounds__(256) void pack_mask_kernel(const void* __restrict__ mask,
                                                        unsigned* __restrict__ bits) {
    __shared__ int isBool;
    if (threadIdx.x == 0) isBool = 0;
    __syncthreads();
    const unsigned char* bytes = (const unsigned char*)mask;
    if (threadIdx.x < 64) {
        if (bytes[threadIdx.x * 4 + 1] | bytes[threadIdx.x * 4 + 2] | bytes[threadIdx.x * 4 + 3])
            isBool = 1;
    }
    __syncthreads();
    int t = blockIdx.x * 256 + threadIdx.x;          // 0..524287
    int half = t & 1, q = (t >> 1) & 2047, kt = (t >> 12) & 31, b = t >> 17;
    size_t src = ((size_t)(b * 2048 + q)) * 2048 + kt * 64 + half * 32;  // element idx
    unsigned v = 0;
    if (isBool) {
        const u32x4* p = (const u32x4*)(bytes + src);     // 32 bytes = 2 x 16B
        u32x4 w0 = p[0], w1 = p[1];
        v = nib4(w0[0]) | (nib4(w0[1]) << 4) | (nib4(w0[2]) << 8) | (nib4(w0[3]) << 12) |
            (nib4(w1[0]) << 16) | (nib4(w1[1]) << 20) | (nib4(w1[2]) << 24) | (nib4(w1[3]) << 28);
    } else {
        const u32x4* p = (const u32x4*)((const int*)mask + src);  // 32 ints = 8 x 16B
        #pragma unroll
        for (int j = 0; j < 8; ++j) {
            u32x4 wv = p[j];
            v |= ((wv[0] ? 1u : 0u) | (wv[1] ? 2u : 0u) | (wv[2] ? 4u : 0u) | (wv[3] ? 8u : 0u)) << (j * 4);
        }
    }
    bits[(((size_t)(b * 32 + kt)) * 2048 + q) * 2 + half] = ~v;   // KEEP bits
}

// ---------------------------------------------------------------------------
// Kernel 2: QKV projection. grid=(M/64, N/64, 3), x over M.
// B operand from pre-transposed bf16 Wt[z][n][k].
// Q out: [b][h][s][dk] bf16 (scaled log2e/8).
// K out: fragment-major K'[(b,h)][kt][ks][hi][key]x8 (16B units).
// V out: fragment-major V'[(b,h)][kt][kb][hi][dv]x8 (16B units).
// ---------------------------------------------------------------------------
__global__ __launch_bounds__(256) void proj_kernel(
    const float* __restrict__ inQ, const float* __restrict__ inK, const float* __restrict__ inV,
    const short* __restrict__ wt,
    short* __restrict__ Qp, short* __restrict__ Kp, short* __restrict__ Vp) {
    __shared__ short As[64 * 64];
    __shared__ short Bs[64 * 64];
    const int z = blockIdx.z;
    const float* A = (z == 0) ? inQ : ((z == 1) ? inK : inV);
    const short* Wz = wt + (size_t)z * 262144;      // [n][k] bf16
    short* O = (z == 0) ? Qp : ((z == 1) ? Kp : Vp);
    const float scale = (z == 0) ? 0.125f * 1.44269504f : 1.0f;   // log2e folded into Q
    const int bm = blockIdx.x * 64, bn = blockIdx.y * 64;
    const int tid = threadIdx.x, lane = tid & 63, wv_ = tid >> 6;
    const int wm = (wv_ >> 1) * 32, wn = (wv_ & 1) * 32;
    f32x4 acc[2][2] = {};

    for (int k0 = 0; k0 < 512; k0 += 64) {
        __syncthreads();
        // stage A: fp32 input, pair-packed bf16
        #pragma unroll
        for (int it = 0; it < 4; ++it) {
            int g = tid + it * 256;
            int r = g >> 4, c4 = (g & 15) * 4;
            f32x4 v = *(const f32x4*)(A + (size_t)(bm + r) * 512 + k0 + c4);
            u32x2 u = { pk2(v.x, v.y), pk2(v.z, v.w) };
            *(u32x2*)((char*)As + r * 128 + ((c4 * 2) ^ ((r & 7) << 4))) = u;
        }
        // stage B: bf16 Wt rows, vectorized (same byte layout as before)
        #pragma unroll
        for (int it = 0; it < 2; ++it) {
            int g = tid + it * 256;
            int n = g >> 3, c8 = (g & 7) * 8;
            short8_t v = *(const short8_t*)(Wz + (size_t)(bn + n) * 512 + k0 + c8);
            *(short8_t*)((char*)Bs + n * 128 + ((c8 * 2) ^ ((n & 7) << 4))) = v;
        }
        __syncthreads();
        #pragma unroll
        for (int kk = 0; kk < 2; ++kk) {
            short8_t af[2], bfr[2];
            #pragma unroll
            for (int rf = 0; rf < 2; ++rf) {
                int row = wm + rf * 16 + (lane & 15);
                af[rf] = *(const short8_t*)((const char*)As + row * 128 +
                          ((kk * 64 + ((lane >> 4) * 16)) ^ ((row & 7) << 4)));
            }
            #pragma unroll
            for (int cf = 0; cf < 2; ++cf) {
                int n = wn + cf * 16 + (lane & 15);
                bfr[cf] = *(const short8_t*)((const char*)Bs + n * 128 +
                           ((kk * 64 + ((lane >> 4) * 16)) ^ ((n & 7) << 4)));
            }
            __builtin_amdgcn_s_setprio(1);
            #pragma unroll
            for (int rf = 0; rf < 2; ++rf)
                #pragma unroll
                for (int cf = 0; cf < 2; ++cf)
                    acc[rf][cf] = __builtin_amdgcn_mfma_f32_16x16x32_bf16(af[rf], bfr[cf], acc[rf][cf], 0, 0, 0);
            __builtin_amdgcn_s_setprio(0);
        }
    }

    if (z == 0) {
        // Q: direct [b][h][s][dk]
        #pragma unroll
        for (int rf = 0; rf < 2; ++rf)
            #pragma unroll
            for (int cf = 0; cf < 2; ++cf)
                #pragma unroll
                for (int r = 0; r < 4; ++r) {
                    int row = bm + wm + rf * 16 + (lane >> 4) * 4 + r;
                    int col = bn + wn + cf * 16 + (lane & 15);
                    size_t idx = ((((size_t)(row >> 11)) * 8 + (col >> 6)) * 2048 + (row & 2047)) * 64 + (col & 63);
                    O[idx] = f2bf(acc[rf][cf][r] * scale);
                }
    } else {
        // K/V: stage to LDS (V transposed), then coalesced fragment-major stores.
        const int bb = bm >> 11, kt = (bm & 2047) >> 6, hh = bn >> 6;
        const size_t base = ((size_t)(bb * 8 + hh)) * 131072 + (size_t)kt * 4096;
        __syncthreads();   // As free (all waves past final mfma)
        if (z == 1) {
            #pragma unroll
            for (int rf = 0; rf < 2; ++rf)
                #pragma unroll
                for (int cf = 0; cf < 2; ++cf)
                    #pragma unroll
                    for (int r = 0; r < 4; ++r) {
                        int key = wm + rf * 16 + (lane >> 4) * 4 + r;
                        int dk = wn + cf * 16 + (lane & 15);
                        *(short*)((char*)As + key * 128 + ((dk * 2) ^ ((key & 7) << 4))) = f2bf(acc[rf][cf][r]);
                    }
        } else {
            #pragma unroll
            for (int rf = 0; rf < 2; ++rf)
                #pragma unroll
                for (int cf = 0; cf < 2; ++cf)
                    #pragma unroll
                    for (int r = 0; r < 4; ++r) {
                        int key = wm + rf * 16 + (lane >> 4) * 4 + r;
                        int dv = wn + cf * 16 + (lane & 15);
                        *(short*)((char*)As + dv * 128 + ((key * 2) ^ ((dv & 7) << 4))) = f2bf(acc[rf][cf][r]);
                    }
        }
        __syncthreads();
        // unit u: [ks|kb](2b) hi(1b) [key|dv](6b); 16B per unit, contiguous out.
        #pragma unroll
        for (int it = 0; it < 2; ++it) {
            int u = tid + it * 256;
            int blk = u >> 7, h2 = (u >> 6) & 1, rr = u & 63;
            short8_t v8 = *(const short8_t*)((const char*)As + rr * 128 +
                           ((blk * 32 + h2 * 16) ^ ((rr & 7) << 4)));
            *(short8_t*)(O + base + (size_t)u * 8) = v8;
        }
    }
}

// ---------------------------------------------------------------------------
// Kernel 3: barrier-free-loop flash attention with in-block split-KV.
// Block = 32 q-rows; wave w handles K-tiles [8w, 8w+8); LDS l-weighted merge.
// grid=(64, 8, 4) = 2048 blocks = 8 blocks/CU.
// ---------------------------------------------------------------------------
__global__ __launch_bounds__(256, 4) void attn_kernel(
    const short* __restrict__ Qp, const short* __restrict__ Kf, const short* __restrict__ Vf,
    const unsigned long long* __restrict__ mbits64, short* __restrict__ ctx) {
    __shared__ short Pw_all[4][2048];    // per-wave normalized partial (16KB)
    __shared__ float l_lds[4][32];
    // XCD-clustered remap: flat%8 ~ XCD; each XCD owns 4 whole (b,h) groups.
    int flat = blockIdx.x + 64 * (blockIdx.y + 8 * blockIdx.z);   // 0..2047
    int x8 = flat & 7, s = flat >> 3;                             // s: 0..255
    int bh = x8 * 4 + (s >> 6);                                   // 0..31
    int qi = s & 63;                                              // 0..63
    const int b = bh >> 3, h = bh & 7;
    const int tid = threadIdx.x, lane = tid & 63, w = tid >> 6;
    const int hi = lane >> 5, r31 = lane & 31;
    const size_t hb = ((size_t)bh) * 131072;
    const int qw = qi * 32;
    const int q_lane = qw + r31;
    const int t_beg = w * 8, t_end = t_beg + 8;

    short8_t qf[4];
    #pragma unroll
    for (int ks = 0; ks < 4; ++ks)
        qf[ks] = *(const short8_t*)(Qp + hb + (size_t)q_lane * 64 + ks * 16 + hi * 8);

    const short* Kb_ = Kf + hb + hi * 512 + r31 * 8;
    const short* Vb_ = Vf + hb + hi * 512 + r31 * 8;
    const unsigned long long* mrow = mbits64 + (size_t)b * 65536 + q_lane;

    f32x16 o0 = {}, o1 = {};
    float l_run = 0.f;

    for (int kt = t_beg; kt < t_end; ++kt) {
        const short* kp = Kb_ + (size_t)kt * 4096;
        unsigned long long wmx = mrow[(size_t)kt * 2048] >> (hi * 4);
        unsigned kl = (unsigned)wmx, kh = (unsigned)(wmx >> 32);

        // QK^T (log2 domain via Q scale)
        f32x16 s0 = {}, s1 = {};
        __builtin_amdgcn_s_setprio(1);
        #pragma unroll
        for (int ks = 0; ks < 4; ++ks) {
            short8_t kf0 = *(const short8_t*)(kp + ks * 1024);
            short8_t kf1 = *(const short8_t*)(kp + ks * 1024 + 256);
            s0 = __builtin_amdgcn_mfma_f32_32x32x16_bf16(kf0, qf[ks], s0, 0, 0, 0);
            s1 = __builtin_amdgcn_mfma_f32_32x32x16_bf16(kf1, qf[ks], s1, 0, 0, 0);
        }
        __builtin_amdgcn_s_setprio(0);

        // p = exp2(s) & keep, in-place; 4-way sum trees
        float r4[4] = { 0.f, 0.f, 0.f, 0.f };
        #pragma unroll
        for (int reg = 0; reg < 16; ++reg) {
            const int pos = (reg >> 2) * 8 + (reg & 3);
            float e0 = __builtin_amdgcn_exp2f(s0[reg]);
            float e1 = __builtin_amdgcn_exp2f(s1[reg]);
            unsigned k0b = (unsigned)__builtin_amdgcn_sbfe((int)kl, pos, 1);
            unsigned k1b = (unsigned)__builtin_amdgcn_sbfe((int)kh, pos, 1);
            float v0 = __builtin_bit_cast(float, __builtin_bit_cast(unsigned, e0) & k0b);
            float v1 = __builtin_bit_cast(float, __builtin_bit_cast(unsigned, e1) & k1b);
            s0[reg] = v0; s1[reg] = v1;
            r4[reg & 3] += v0 + v1;
        }
        float rs = (r4[0] + r4[1]) + (r4[2] + r4[3]);
        rs += __shfl_xor(rs, 32, 64);
        l_run += rs;

        // PV: O^T += V^T . P^T
        const short* vp = Vb_ + (size_t)kt * 4096;
        #pragma unroll
        for (int kb = 0; kb < 4; ++kb) {
            const int e = (kb & 1) * 8;
            unsigned c0 = (kb < 2) ? pk2(s0[e + 0], s0[e + 1]) : pk2(s1[e + 0], s1[e + 1]);
            unsigned c1 = (kb < 2) ? pk2(s0[e + 2], s0[e + 3]) : pk2(s1[e + 2], s1[e + 3]);
            unsigned c2 = (kb < 2) ? pk2(s0[e + 4], s0[e + 5]) : pk2(s1[e + 4], s1[e + 5]);
            unsigned c3 = (kb < 2) ? pk2(s0[e + 6], s0[e + 7]) : pk2(s1[e + 6], s1[e + 7]);
#if __has_builtin(__builtin_amdgcn_permlane32_swap)
            u32x2 r02 = __builtin_amdgcn_permlane32_swap(c0, c2, false, false);
            u32x2 r13 = __builtin_amdgcn_permlane32_swap(c1, c3, false, false);
            u32x4 bw = { r02[0], r13[0], r02[1], r13[1] };
#else
            unsigned x0 = __shfl_xor(c0, 32, 64), x1 = __shfl_xor(c1, 32, 64);
            unsigned x2 = __shfl_xor(c2, 32, 64), x3 = __shfl_xor(c3, 32, 64);
            unsigned w0 = hi ? x2 : c0, w1 = hi ? x3 : c1;
            unsigned w2 = hi ? c2 : x0, w3 = hi ? c3 : x1;
            u32x4 bw = { w0, w1, w2, w3 };
#endif
            short8_t pb = __builtin_bit_cast(short8_t, bw);
            short8_t vf0 = *(const short8_t*)(vp + kb * 1024);
            short8_t vf1 = *(const short8_t*)(vp + kb * 1024 + 256);
            __builtin_amdgcn_s_setprio(1);
            o0 = __builtin_amdgcn_mfma_f32_32x32x16_bf16(vf0, pb, o0, 0, 0, 0);
            o1 = __builtin_amdgcn_mfma_f32_32x32x16_bf16(vf1, pb, o1, 0, 0, 0);
            __builtin_amdgcn_s_setprio(0);
        }
    }

    // per-wave epilogue: normalize + transpose into LDS, post l
    float invl = 1.0f / fmaxf(l_run, 1e-37f);
    short* Pw = Pw_all[w];
    #pragma unroll
    for (int dvb = 0; dvb < 2; ++dvb)
        #pragma unroll
        for (int g = 0; g < 4; ++g) {
            short4_t v4;
            #pragma unroll
            for (int t = 0; t < 4; ++t) {
                float val = (dvb ? o1[g * 4 + t] : o0[g * 4 + t]) * invl;
                v4[t] = f2bf(val);
            }
            int dv0 = dvb * 32 + g * 8 + hi * 4;
            *(short4_t*)((char*)Pw + r31 * 128 + ((dv0 * 2) ^ ((r31 & 7) << 4))) = v4;
        }
    if (hi == 0) l_lds[w][r31] = l_run;
    __syncthreads();

    // block epilogue: l-weighted merge of the 4 wave partials -> ctx
    const int q = tid >> 3, j = tid & 7;
    float acc8[8] = {};
    float wsum = 0.f;
    #pragma unroll
    for (int ww = 0; ww < 4; ++ww) {
        float lw = l_lds[ww][q];
        wsum += lw;
        short8_t v8 = *(const short8_t*)((const char*)Pw_all[ww] + q * 128 + ((j * 16) ^ ((q & 7) << 4)));
        #pragma unroll
        for (int e = 0; e < 8; ++e)
            acc8[e] += bf2f(v8[e]) * lw;
    }
    float inv = 1.f / fmaxf(wsum, 1e-37f);
    u32x4 ov = { pk2(acc8[0] * inv, acc8[1] * inv), pk2(acc8[2] * inv, acc8[3] * inv),
                 pk2(acc8[4] * inv, acc8[5] * inv), pk2(acc8[6] * inv, acc8[7] * inv) };
    *(short8_t*)(ctx + ((size_t)(b * 2048 + qw + q)) * 512 + h * 64 + j * 8) =
        __builtin_bit_cast(short8_t, ov);
}

// ---------------------------------------------------------------------------
// Kernel 4: FC + residual. grid=(M/64, N/64), x over M. 64x64 tile.
// B operand from pre-transposed bf16 Wt[3][n][k].
// ---------------------------------------------------------------------------
__global__ __launch_bounds__(256) void fc_kernel(
    const short* __restrict__ ctx, const short* __restrict__ wtfc,
    const float* __restrict__ inQ, float* __restrict__ xbuf) {
    __shared__ short As[64 * 64];
    __shared__ short Bs[64 * 64];
    const int bm = blockIdx.x * 64, bn = blockIdx.y * 64;
    const int tid = threadIdx.x, lane = tid & 63, wv_ = tid >> 6;
    const int wm = (wv_ >> 1) * 32, wn = (wv_ & 1) * 32;
    f32x4 acc[2][2] = {};

    for (int k0 = 0; k0 < 512; k0 += 64) {
        __syncthreads();
        #pragma unroll
        for (int it = 0; it < 2; ++it) {
            int g = tid + it * 256;
            int r = g >> 3, c8 = (g & 7) * 8;
            short8_t v = *(const short8_t*)(ctx + (size_t)(bm + r) * 512 + k0 + c8);
            *(short8_t*)((char*)As + r * 128 + ((c8 * 2) ^ ((r & 7) << 4))) = v;
        }
        #pragma unroll
        for (int it = 0; it < 2; ++it) {
            int g = tid + it * 256;
            int n = g >> 3, c8 = (g & 7) * 8;
            short8_t v = *(const short8_t*)(wtfc + (size_t)(bn + n) * 512 + k0 + c8);
            *(short8_t*)((char*)Bs + n * 128 + ((c8 * 2) ^ ((n & 7) << 4))) = v;
        }
        __syncthreads();
        #pragma unroll
        for (int kk = 0; kk < 2; ++kk) {
            short8_t af[2], bfr[2];
            #pragma unroll
            for (int rf = 0; rf < 2; ++rf) {
                int row = wm + rf * 16 + (lane & 15);
                af[rf] = *(const short8_t*)((const char*)As + row * 128 +
                          ((kk * 64 + ((lane >> 4) * 16)) ^ ((row & 7) << 4)));
            }
            #pragma unroll
            for (int cf = 0; cf < 2; ++cf) {
                int n = wn + cf * 16 + (lane & 15);
                bfr[cf] = *(const short8_t*)((const char*)Bs + n * 128 +
                           ((kk * 64 + ((lane >> 4) * 16)) ^ ((n & 7) << 4)));
            }
            __builtin_amdgcn_s_setprio(1);
            #pragma unroll
            for (int rf = 0; rf < 2; ++rf)
                #pragma unroll
                for (int cf = 0; cf < 2; ++cf)
                    acc[rf][cf] = __builtin_amdgcn_mfma_f32_16x16x32_bf16(af[rf], bfr[cf], acc[rf][cf], 0, 0, 0);
            __builtin_amdgcn_s_setprio(0);
        }
    }
    #pragma unroll
    for (int rf = 0; rf < 2; ++rf)
        #pragma unroll
        for (int cf = 0; cf < 2; ++cf)
            #pragma unroll
            for (int r = 0; r < 4; ++r) {
                int row = bm + wm + rf * 16 + (lane >> 4) * 4 + r;
                int col = bn + wn + cf * 16 + (lane & 15);
                size_t idx = (size_t)row * 512 + col;
                xbuf[idx] = acc[rf][cf][r] + inQ[idx];
            }
}

// ---------------------------------------------------------------------------
// Kernel 5: LayerNorm over D=512. Wave-per-row, no LDS, no barriers.
// grid=2048, 4 rows/block.
// ---------------------------------------------------------------------------
__global__ __launch_bounds__(256) void ln_kernel(
    const float* __restrict__ x, const float* __restrict__ gamma,
    const float* __restrict__ beta, float* __restrict__ out) {
    const int w = threadIdx.x >> 6, lane = threadIdx.x & 63;
    const int row = blockIdx.x * 4 + w;
    const f32x4* xr = (const f32x4*)(x + (size_t)row * 512);
    f32x4 a = xr[lane * 2], bb = xr[lane * 2 + 1];
    float s = (a.x + a.y) + (a.z + a.w) + (bb.x + bb.y) + (bb.z + bb.w);
    float sq = a.x * a.x + a.y * a.y + a.z * a.z + a.w * a.w +
               bb.x * bb.x + bb.y * bb.y + bb.z * bb.z + bb.w * bb.w;
    #pragma unroll
    for (int off = 32; off; off >>= 1) {
        s += __shfl_xor(s, off, 64);
        sq += __shfl_xor(sq, off, 64);
    }
    float mean = s * (1.f / 512.f);
    float var = sq * (1.f / 512.f) - mean * mean;
    float inv = rsqrtf(var + 1e-5f);
    const f32x4* gr = (const f32x4*)gamma;
    const f32x4* br = (const f32x4*)beta;
    f32x4 g0 = gr[lane * 2], g1 = gr[lane * 2 + 1];
    f32x4 b0 = br[lane * 2], b1 = br[lane * 2 + 1];
    f32x4 o0, o1;
    o0.x = (a.x - mean) * inv * g0.x + b0.x;
    o0.y = (a.y - mean) * inv * g0.y + b0.y;
    o0.z = (a.z - mean) * inv * g0.z + b0.z;
    o0.w = (a.w - mean) * inv * g0.w + b0.w;
    o1.x = (bb.x - mean) * inv * g1.x + b1.x;
    o1.y = (bb.y - mean) * inv * g1.y + b1.y;
    o1.z = (bb.z - mean) * inv * g1.z + b1.z;
    o1.w = (bb.w - mean) * inv * g1.w + b1.w;
    f32x4* orow = (f32x4*)(out + (size_t)row * 512);
    orow[lane * 2] = o0;
    orow[lane * 2 + 1] = o1;
}

// ---------------------------------------------------------------------------
extern "C" void kernel_launch(void* const* d_in, const int* in_sizes, int n_in,
                              void* d_out, int out_size, void* d_ws, size_t ws_size,
                              hipStream_t stream) {
    const float* inQ = (const float*)d_in[0];
    const float* inK = (const float*)d_in[1];
    const float* inV = (const float*)d_in[2];
    const void* mask = d_in[3];
    const float* wq = (const float*)d_in[4];
    const float* wk = (const float*)d_in[5];
    const float* wv = (const float*)d_in[6];
    const float* wfc = (const float*)d_in[7];
    const float* gamma = (const float*)d_in[8];
    const float* beta = (const float*)d_in[9];
    float* out = (float*)d_out;
    char* ws = (char*)d_ws;

    short* Qp = (short*)(ws);                          // 8 MB
    short* Kp = (short*)(ws + (size_t)(8 << 20));      // 8 MB, fragment-major
    short* Vp = (short*)(ws + (size_t)(16 << 20));     // 8 MB, fragment-major
    short* ctx = (short*)(ws + (size_t)(24 << 20));    // 8 MB
    unsigned* mbits = (unsigned*)(ws + (size_t)(32 << 20)); // 2 MB
    short* wt = (short*)(ws + (size_t)(34 << 20));     // 2 MB: 4 x [512][512] bf16 [n][k]
    float* xbuf = (float*)(ws);                        // 16 MB, reuses Qp/Kp (dead after attn)

    wprep_kernel<<<dim3(8, 8, 4), 256, 0, stream>>>(wq, wk, wv, wfc, wt);
    pack_mask_kernel<<<2048, 256, 0, stream>>>(mask, mbits);
    proj_kernel<<<dim3(128, 8, 3), 256, 0, stream>>>(inQ, inK, inV, wt, Qp, Kp, Vp);
    attn_kernel<<<dim3(64, 8, 4), 256, 0, stream>>>(
        Qp, Kp, Vp, (const unsigned long long*)mbits, ctx);
    fc_kernel<<<dim3(128, 8, 1), 256, 0, stream>>>(ctx, wt + 3 * 262144, inQ, xbuf);
    ln_kernel<<<2048, 256, 0, stream>>>(xbuf, gamma, beta, out);
}

// Round 19
// 125.017 us; speedup vs baseline: 1.2701x; 1.0142x over previous
//
#include <hip/hip_runtime.h>

// FullAttention fused pipeline for MI355X (gfx950).
// B=4 S=2048 D=512 H=8 DK=DV=64.
// Round 19: bf16 intermediate x (fc writes bf16, ln reads bf16) — saves
// ~16MB HBM on the xbuf roundtrip. Everything else byte-identical to
// round 18 (126.8us best: wprep'd weights, fragment-major K/V, barrier-free
// in-block-split attn).

#define B_ 4
#define S_ 2048
#define D_ 512
#define H_ 8

typedef __attribute__((ext_vector_type(8))) short short8_t;
typedef __attribute__((ext_vector_type(4))) short short4_t;
typedef __attribute__((ext_vector_type(4))) float f32x4;
typedef __attribute__((ext_vector_type(16))) float f32x16;
typedef __attribute__((ext_vector_type(4))) unsigned u32x4;
typedef __attribute__((ext_vector_type(2))) unsigned u32x2;

__device__ __forceinline__ short f2bf(float f) {
    unsigned u = __builtin_bit_cast(unsigned, f);
    u += 0x7fff + ((u >> 16) & 1);   // RNE
    return (short)(u >> 16);
}

// pack two f32 -> two bf16 (truncation) via one v_perm_b32
__device__ __forceinline__ unsigned pk2(float a, float b) {
    return __builtin_amdgcn_perm(__builtin_bit_cast(unsigned, b),
                                 __builtin_bit_cast(unsigned, a), 0x07060302u);
}

__device__ __forceinline__ float bf2f(short v) {
    return __builtin_bit_cast(float, (unsigned)((unsigned short)v) << 16);
}

// 4 bytes -> 4 bits (bit i = byte i nonzero)
__device__ __forceinline__ unsigned nib4(unsigned w4) {
    unsigned t = (w4 & 0x7f7f7f7fu) + 0x7f7f7f7fu;
    t |= w4;
    return (((t >> 7) & 0x01010101u) * 0x01020408u) >> 24;
}

// ---------------------------------------------------------------------------
// Kernel 0: weight prep. 4 matrices (wq,wk,wv,wfc) fp32 [k][n] -> bf16 [n][k].
// grid=(8,8,4): (k-tile, n-tile, matrix). Stage+de-swizzle via LDS.
// ---------------------------------------------------------------------------
__global__ __launch_bounds__(256) void wprep_kernel(
    const float* __restrict__ wq, const float* __restrict__ wk,
    const float* __restrict__ wv, const float* __restrict__ wfc,
    short* __restrict__ wt) {
    __shared__ short Bs[64 * 64];
    const int k0 = blockIdx.x * 64, n0 = blockIdx.y * 64, m = blockIdx.z;
    const float* W = (m == 0) ? wq : ((m == 1) ? wk : ((m == 2) ? wv : wfc));
    const int tid = threadIdx.x;
    #pragma unroll
    for (int it = 0; it < 2; ++it) {
        int g = tid + it * 256;
        int kp = g >> 4, n4 = (g & 15) * 4;
        const float* wrow = W + (size_t)(k0 + 2 * kp) * 512 + n0 + n4;
        f32x4 va = *(const f32x4*)(wrow);
        f32x4 vb = *(const f32x4*)(wrow + 512);
        #pragma unroll
        for (int j = 0; j < 4; ++j) {
            int n = n4 + j;
            *(unsigned*)((char*)Bs + n * 128 + ((4 * kp) ^ ((n & 7) << 4))) = pk2(va[j], vb[j]);
        }
    }
    __syncthreads();
    #pragma unroll
    for (int it = 0; it < 2; ++it) {
        int g = tid + it * 256;                 // 512 groups of 8
        int n = g >> 3, c8 = (g & 7) * 8;
        short8_t v = *(const short8_t*)((const char*)Bs + n * 128 + ((c8 * 2) ^ ((n & 7) << 4)));
        *(short8_t*)(wt + ((size_t)m * 512 + n0 + n) * 512 + k0 + c8) = v;
    }
}

// ---------------------------------------------------------------------------
// Kernel 1: mask detect (bool-1B vs int32) + bit-pack INVERTED (bit=KEEP),
// relayout to [(b*32+kt)*2048 + q] u64 words. Vectorized loads.
// ---------------------------------------------------------------------------
__global__ __launch_bounds__(256) void pack_mask_kernel(const void* __restrict__ mask,
                                                        unsigned* __restrict__ bits) {
    __shared__ int isBool;
    if (threadIdx.x == 0) isBool = 0;
    __syncthreads();
    const unsigned char* bytes = (const unsigned char*)mask;
    if (threadIdx.x < 64) {
        if (bytes[threadIdx.x * 4 + 1] | bytes[threadIdx.x * 4 + 2] | bytes[threadIdx.x * 4 + 3])
            isBool = 1;
    }
    __syncthreads();
    int t = blockIdx.x * 256 + threadIdx.x;          // 0..524287
    int half = t & 1, q = (t >> 1) & 2047, kt = (t >> 12) & 31, b = t >> 17;
    size_t src = ((size_t)(b * 2048 + q)) * 2048 + kt * 64 + half * 32;  // element idx
    unsigned v = 0;
    if (isBool) {
        const u32x4* p = (const u32x4*)(bytes + src);     // 32 bytes = 2 x 16B
        u32x4 w0 = p[0], w1 = p[1];
        v = nib4(w0[0]) | (nib4(w0[1]) << 4) | (nib4(w0[2]) << 8) | (nib4(w0[3]) << 12) |
            (nib4(w1[0]) << 16) | (nib4(w1[1]) << 20) | (nib4(w1[2]) << 24) | (nib4(w1[3]) << 28);
    } else {
        const u32x4* p = (const u32x4*)((const int*)mask + src);  // 32 ints = 8 x 16B
        #pragma unroll
        for (int j = 0; j < 8; ++j) {
            u32x4 wv = p[j];
            v |= ((wv[0] ? 1u : 0u) | (wv[1] ? 2u : 0u) | (wv[2] ? 4u : 0u) | (wv[3] ? 8u : 0u)) << (j * 4);
        }
    }
    bits[(((size_t)(b * 32 + kt)) * 2048 + q) * 2 + half] = ~v;   // KEEP bits
}

// ---------------------------------------------------------------------------
// Kernel 2: QKV projection. grid=(M/64, N/64, 3), x over M.
// B operand from pre-transposed bf16 Wt[z][n][k].
// Q out: [b][h][s][dk] bf16 (scaled log2e/8).
// K out: fragment-major K'[(b,h)][kt][ks][hi][key]x8 (16B units).
// V out: fragment-major V'[(b,h)][kt][kb][hi][dv]x8 (16B units).
// ---------------------------------------------------------------------------
__global__ __launch_bounds__(256) void proj_kernel(
    const float* __restrict__ inQ, const float* __restrict__ inK, const float* __restrict__ inV,
    const short* __restrict__ wt,
    short* __restrict__ Qp, short* __restrict__ Kp, short* __restrict__ Vp) {
    __shared__ short As[64 * 64];
    __shared__ short Bs[64 * 64];
    const int z = blockIdx.z;
    const float* A = (z == 0) ? inQ : ((z == 1) ? inK : inV);
    const short* Wz = wt + (size_t)z * 262144;      // [n][k] bf16
    short* O = (z == 0) ? Qp : ((z == 1) ? Kp : Vp);
    const float scale = (z == 0) ? 0.125f * 1.44269504f : 1.0f;   // log2e folded into Q
    const int bm = blockIdx.x * 64, bn = blockIdx.y * 64;
    const int tid = threadIdx.x, lane = tid & 63, wv_ = tid >> 6;
    const int wm = (wv_ >> 1) * 32, wn = (wv_ & 1) * 32;
    f32x4 acc[2][2] = {};

    for (int k0 = 0; k0 < 512; k0 += 64) {
        __syncthreads();
        // stage A: fp32 input, pair-packed bf16
        #pragma unroll
        for (int it = 0; it < 4; ++it) {
            int g = tid + it * 256;
            int r = g >> 4, c4 = (g & 15) * 4;
            f32x4 v = *(const f32x4*)(A + (size_t)(bm + r) * 512 + k0 + c4);
            u32x2 u = { pk2(v.x, v.y), pk2(v.z, v.w) };
            *(u32x2*)((char*)As + r * 128 + ((c4 * 2) ^ ((r & 7) << 4))) = u;
        }
        // stage B: bf16 Wt rows, vectorized
        #pragma unroll
        for (int it = 0; it < 2; ++it) {
            int g = tid + it * 256;
            int n = g >> 3, c8 = (g & 7) * 8;
            short8_t v = *(const short8_t*)(Wz + (size_t)(bn + n) * 512 + k0 + c8);
            *(short8_t*)((char*)Bs + n * 128 + ((c8 * 2) ^ ((n & 7) << 4))) = v;
        }
        __syncthreads();
        #pragma unroll
        for (int kk = 0; kk < 2; ++kk) {
            short8_t af[2], bfr[2];
            #pragma unroll
            for (int rf = 0; rf < 2; ++rf) {
                int row = wm + rf * 16 + (lane & 15);
                af[rf] = *(const short8_t*)((const char*)As + row * 128 +
                          ((kk * 64 + ((lane >> 4) * 16)) ^ ((row & 7) << 4)));
            }
            #pragma unroll
            for (int cf = 0; cf < 2; ++cf) {
                int n = wn + cf * 16 + (lane & 15);
                bfr[cf] = *(const short8_t*)((const char*)Bs + n * 128 +
                           ((kk * 64 + ((lane >> 4) * 16)) ^ ((n & 7) << 4)));
            }
            __builtin_amdgcn_s_setprio(1);
            #pragma unroll
            for (int rf = 0; rf < 2; ++rf)
                #pragma unroll
                for (int cf = 0; cf < 2; ++cf)
                    acc[rf][cf] = __builtin_amdgcn_mfma_f32_16x16x32_bf16(af[rf], bfr[cf], acc[rf][cf], 0, 0, 0);
            __builtin_amdgcn_s_setprio(0);
        }
    }

    if (z == 0) {
        // Q: direct [b][h][s][dk]
        #pragma unroll
        for (int rf = 0; rf < 2; ++rf)
            #pragma unroll
            for (int cf = 0; cf < 2; ++cf)
                #pragma unroll
                for (int r = 0; r < 4; ++r) {
                    int row = bm + wm + rf * 16 + (lane >> 4) * 4 + r;
                    int col = bn + wn + cf * 16 + (lane & 15);
                    size_t idx = ((((size_t)(row >> 11)) * 8 + (col >> 6)) * 2048 + (row & 2047)) * 64 + (col & 63);
                    O[idx] = f2bf(acc[rf][cf][r] * scale);
                }
    } else {
        // K/V: stage to LDS (V transposed), then coalesced fragment-major stores.
        const int bb = bm >> 11, kt = (bm & 2047) >> 6, hh = bn >> 6;
        const size_t base = ((size_t)(bb * 8 + hh)) * 131072 + (size_t)kt * 4096;
        __syncthreads();   // As free (all waves past final mfma)
        if (z == 1) {
            #pragma unroll
            for (int rf = 0; rf < 2; ++rf)
                #pragma unroll
                for (int cf = 0; cf < 2; ++cf)
                    #pragma unroll
                    for (int r = 0; r < 4; ++r) {
                        int key = wm + rf * 16 + (lane >> 4) * 4 + r;
                        int dk = wn + cf * 16 + (lane & 15);
                        *(short*)((char*)As + key * 128 + ((dk * 2) ^ ((key & 7) << 4))) = f2bf(acc[rf][cf][r]);
                    }
        } else {
            #pragma unroll
            for (int rf = 0; rf < 2; ++rf)
                #pragma unroll
                for (int cf = 0; cf < 2; ++cf)
                    #pragma unroll
                    for (int r = 0; r < 4; ++r) {
                        int key = wm + rf * 16 + (lane >> 4) * 4 + r;
                        int dv = wn + cf * 16 + (lane & 15);
                        *(short*)((char*)As + dv * 128 + ((key * 2) ^ ((dv & 7) << 4))) = f2bf(acc[rf][cf][r]);
                    }
        }
        __syncthreads();
        // unit u: [ks|kb](2b) hi(1b) [key|dv](6b); 16B per unit, contiguous out.
        #pragma unroll
        for (int it = 0; it < 2; ++it) {
            int u = tid + it * 256;
            int blk = u >> 7, h2 = (u >> 6) & 1, rr = u & 63;
            short8_t v8 = *(const short8_t*)((const char*)As + rr * 128 +
                           ((blk * 32 + h2 * 16) ^ ((rr & 7) << 4)));
            *(short8_t*)(O + base + (size_t)u * 8) = v8;
        }
    }
}

// ---------------------------------------------------------------------------
// Kernel 3: barrier-free-loop flash attention with in-block split-KV.
// Block = 32 q-rows; wave w handles K-tiles [8w, 8w+8); LDS l-weighted merge.
// grid=(64, 8, 4) = 2048 blocks = 8 blocks/CU.
// ---------------------------------------------------------------------------
__global__ __launch_bounds__(256, 4) void attn_kernel(
    const short* __restrict__ Qp, const short* __restrict__ Kf, const short* __restrict__ Vf,
    const unsigned long long* __restrict__ mbits64, short* __restrict__ ctx) {
    __shared__ short Pw_all[4][2048];    // per-wave normalized partial (16KB)
    __shared__ float l_lds[4][32];
    // XCD-clustered remap: flat%8 ~ XCD; each XCD owns 4 whole (b,h) groups.
    int flat = blockIdx.x + 64 * (blockIdx.y + 8 * blockIdx.z);   // 0..2047
    int x8 = flat & 7, s = flat >> 3;                             // s: 0..255
    int bh = x8 * 4 + (s >> 6);                                   // 0..31
    int qi = s & 63;                                              // 0..63
    const int b = bh >> 3, h = bh & 7;
    const int tid = threadIdx.x, lane = tid & 63, w = tid >> 6;
    const int hi = lane >> 5, r31 = lane & 31;
    const size_t hb = ((size_t)bh) * 131072;
    const int qw = qi * 32;
    const int q_lane = qw + r31;
    const int t_beg = w * 8, t_end = t_beg + 8;

    short8_t qf[4];
    #pragma unroll
    for (int ks = 0; ks < 4; ++ks)
        qf[ks] = *(const short8_t*)(Qp + hb + (size_t)q_lane * 64 + ks * 16 + hi * 8);

    const short* Kb_ = Kf + hb + hi * 512 + r31 * 8;
    const short* Vb_ = Vf + hb + hi * 512 + r31 * 8;
    const unsigned long long* mrow = mbits64 + (size_t)b * 65536 + q_lane;

    f32x16 o0 = {}, o1 = {};
    float l_run = 0.f;

    for (int kt = t_beg; kt < t_end; ++kt) {
        const short* kp = Kb_ + (size_t)kt * 4096;
        unsigned long long wmx = mrow[(size_t)kt * 2048] >> (hi * 4);
        unsigned kl = (unsigned)wmx, kh = (unsigned)(wmx >> 32);

        // QK^T (log2 domain via Q scale)
        f32x16 s0 = {}, s1 = {};
        __builtin_amdgcn_s_setprio(1);
        #pragma unroll
        for (int ks = 0; ks < 4; ++ks) {
            short8_t kf0 = *(const short8_t*)(kp + ks * 1024);
            short8_t kf1 = *(const short8_t*)(kp + ks * 1024 + 256);
            s0 = __builtin_amdgcn_mfma_f32_32x32x16_bf16(kf0, qf[ks], s0, 0, 0, 0);
            s1 = __builtin_amdgcn_mfma_f32_32x32x16_bf16(kf1, qf[ks], s1, 0, 0, 0);
        }
        __builtin_amdgcn_s_setprio(0);

        // p = exp2(s) & keep, in-place; 4-way sum trees
        float r4[4] = { 0.f, 0.f, 0.f, 0.f };
        #pragma unroll
        for (int reg = 0; reg < 16; ++reg) {
            const int pos = (reg >> 2) * 8 + (reg & 3);
            float e0 = __builtin_amdgcn_exp2f(s0[reg]);
            float e1 = __builtin_amdgcn_exp2f(s1[reg]);
            unsigned k0b = (unsigned)__builtin_amdgcn_sbfe((int)kl, pos, 1);
            unsigned k1b = (unsigned)__builtin_amdgcn_sbfe((int)kh, pos, 1);
            float v0 = __builtin_bit_cast(float, __builtin_bit_cast(unsigned, e0) & k0b);
            float v1 = __builtin_bit_cast(float, __builtin_bit_cast(unsigned, e1) & k1b);
            s0[reg] = v0; s1[reg] = v1;
            r4[reg & 3] += v0 + v1;
        }
        float rs = (r4[0] + r4[1]) + (r4[2] + r4[3]);
        rs += __shfl_xor(rs, 32, 64);
        l_run += rs;

        // PV: O^T += V^T . P^T
        const short* vp = Vb_ + (size_t)kt * 4096;
        #pragma unroll
        for (int kb = 0; kb < 4; ++kb) {
            const int e = (kb & 1) * 8;
            unsigned c0 = (kb < 2) ? pk2(s0[e + 0], s0[e + 1]) : pk2(s1[e + 0], s1[e + 1]);
            unsigned c1 = (kb < 2) ? pk2(s0[e + 2], s0[e + 3]) : pk2(s1[e + 2], s1[e + 3]);
            unsigned c2 = (kb < 2) ? pk2(s0[e + 4], s0[e + 5]) : pk2(s1[e + 4], s1[e + 5]);
            unsigned c3 = (kb < 2) ? pk2(s0[e + 6], s0[e + 7]) : pk2(s1[e + 6], s1[e + 7]);
#if __has_builtin(__builtin_amdgcn_permlane32_swap)
            u32x2 r02 = __builtin_amdgcn_permlane32_swap(c0, c2, false, false);
            u32x2 r13 = __builtin_amdgcn_permlane32_swap(c1, c3, false, false);
            u32x4 bw = { r02[0], r13[0], r02[1], r13[1] };
#else
            unsigned x0 = __shfl_xor(c0, 32, 64), x1 = __shfl_xor(c1, 32, 64);
            unsigned x2 = __shfl_xor(c2, 32, 64), x3 = __shfl_xor(c3, 32, 64);
            unsigned w0 = hi ? x2 : c0, w1 = hi ? x3 : c1;
            unsigned w2 = hi ? c2 : x0, w3 = hi ? c3 : x1;
            u32x4 bw = { w0, w1, w2, w3 };
#endif
            short8_t pb = __builtin_bit_cast(short8_t, bw);
            short8_t vf0 = *(const short8_t*)(vp + kb * 1024);
            short8_t vf1 = *(const short8_t*)(vp + kb * 1024 + 256);
            __builtin_amdgcn_s_setprio(1);
            o0 = __builtin_amdgcn_mfma_f32_32x32x16_bf16(vf0, pb, o0, 0, 0, 0);
            o1 = __builtin_amdgcn_mfma_f32_32x32x16_bf16(vf1, pb, o1, 0, 0, 0);
            __builtin_amdgcn_s_setprio(0);
        }
    }

    // per-wave epilogue: normalize + transpose into LDS, post l
    float invl = 1.0f / fmaxf(l_run, 1e-37f);
    short* Pw = Pw_all[w];
    #pragma unroll
    for (int dvb = 0; dvb < 2; ++dvb)
        #pragma unroll
        for (int g = 0; g < 4; ++g) {
            short4_t v4;
            #pragma unroll
            for (int t = 0; t < 4; ++t) {
                float val = (dvb ? o1[g * 4 + t] : o0[g * 4 + t]) * invl;
                v4[t] = f2bf(val);
            }
            int dv0 = dvb * 32 + g * 8 + hi * 4;
            *(short4_t*)((char*)Pw + r31 * 128 + ((dv0 * 2) ^ ((r31 & 7) << 4))) = v4;
        }
    if (hi == 0) l_lds[w][r31] = l_run;
    __syncthreads();

    // block epilogue: l-weighted merge of the 4 wave partials -> ctx
    const int q = tid >> 3, j = tid & 7;
    float acc8[8] = {};
    float wsum = 0.f;
    #pragma unroll
    for (int ww = 0; ww < 4; ++ww) {
        float lw = l_lds[ww][q];
        wsum += lw;
        short8_t v8 = *(const short8_t*)((const char*)Pw_all[ww] + q * 128 + ((j * 16) ^ ((q & 7) << 4)));
        #pragma unroll
        for (int e = 0; e < 8; ++e)
            acc8[e] += bf2f(v8[e]) * lw;
    }
    float inv = 1.f / fmaxf(wsum, 1e-37f);
    u32x4 ov = { pk2(acc8[0] * inv, acc8[1] * inv), pk2(acc8[2] * inv, acc8[3] * inv),
                 pk2(acc8[4] * inv, acc8[5] * inv), pk2(acc8[6] * inv, acc8[7] * inv) };
    *(short8_t*)(ctx + ((size_t)(b * 2048 + qw + q)) * 512 + h * 64 + j * 8) =
        __builtin_bit_cast(short8_t, ov);
}

// ---------------------------------------------------------------------------
// Kernel 4: FC + residual. grid=(M/64, N/64), x over M. 64x64 tile.
// B operand from pre-transposed bf16 Wt[3][n][k]. Writes x as bf16.
// ---------------------------------------------------------------------------
__global__ __launch_bounds__(256) void fc_kernel(
    const short* __restrict__ ctx, const short* __restrict__ wtfc,
    const float* __restrict__ inQ, short* __restrict__ xb) {
    __shared__ short As[64 * 64];
    __shared__ short Bs[64 * 64];
    const int bm = blockIdx.x * 64, bn = blockIdx.y * 64;
    const int tid = threadIdx.x, lane = tid & 63, wv_ = tid >> 6;
    const int wm = (wv_ >> 1) * 32, wn = (wv_ & 1) * 32;
    f32x4 acc[2][2] = {};

    for (int k0 = 0; k0 < 512; k0 += 64) {
        __syncthreads();
        #pragma unroll
        for (int it = 0; it < 2; ++it) {
            int g = tid + it * 256;
            int r = g >> 3, c8 = (g & 7) * 8;
            short8_t v = *(const short8_t*)(ctx + (size_t)(bm + r) * 512 + k0 + c8);
            *(short8_t*)((char*)As + r * 128 + ((c8 * 2) ^ ((r & 7) << 4))) = v;
        }
        #pragma unroll
        for (int it = 0; it < 2; ++it) {
            int g = tid + it * 256;
            int n = g >> 3, c8 = (g & 7) * 8;
            short8_t v = *(const short8_t*)(wtfc + (size_t)(bn + n) * 512 + k0 + c8);
            *(short8_t*)((char*)Bs + n * 128 + ((c8 * 2) ^ ((n & 7) << 4))) = v;
        }
        __syncthreads();
        #pragma unroll
        for (int kk = 0; kk < 2; ++kk) {
            short8_t af[2], bfr[2];
            #pragma unroll
            for (int rf = 0; rf < 2; ++rf) {
                int row = wm + rf * 16 + (lane & 15);
                af[rf] = *(const short8_t*)((const char*)As + row * 128 +
                          ((kk * 64 + ((lane >> 4) * 16)) ^ ((row & 7) << 4)));
            }
            #pragma unroll
            for (int cf = 0; cf < 2; ++cf) {
                int n = wn + cf * 16 + (lane & 15);
                bfr[cf] = *(const short8_t*)((const char*)Bs + n * 128 +
                           ((kk * 64 + ((lane >> 4) * 16)) ^ ((n & 7) << 4)));
            }
            __builtin_amdgcn_s_setprio(1);
            #pragma unroll
            for (int rf = 0; rf < 2; ++rf)
                #pragma unroll
                for (int cf = 0; cf < 2; ++cf)
                    acc[rf][cf] = __builtin_amdgcn_mfma_f32_16x16x32_bf16(af[rf], bfr[cf], acc[rf][cf], 0, 0, 0);
            __builtin_amdgcn_s_setprio(0);
        }
    }
    #pragma unroll
    for (int rf = 0; rf < 2; ++rf)
        #pragma unroll
        for (int cf = 0; cf < 2; ++cf)
            #pragma unroll
            for (int r = 0; r < 4; ++r) {
                int row = bm + wm + rf * 16 + (lane >> 4) * 4 + r;
                int col = bn + wn + cf * 16 + (lane & 15);
                size_t idx = (size_t)row * 512 + col;
                xb[idx] = f2bf(acc[rf][cf][r] + inQ[idx]);
            }
}

// ---------------------------------------------------------------------------
// Kernel 5: LayerNorm over D=512 on bf16 x. Wave-per-row, no LDS, no barriers.
// grid=2048, 4 rows/block; one short8 (8 cols) per lane.
// ---------------------------------------------------------------------------
__global__ __launch_bounds__(256) void ln_kernel(
    const short* __restrict__ xb, const float* __restrict__ gamma,
    const float* __restrict__ beta, float* __restrict__ out) {
    const int w = threadIdx.x >> 6, lane = threadIdx.x & 63;
    const int row = blockIdx.x * 4 + w;
    short8_t xv8 = *(const short8_t*)(xb + (size_t)row * 512 + lane * 8);
    float xv[8];
    float s = 0.f, sq = 0.f;
    #pragma unroll
    for (int j = 0; j < 8; ++j) {
        xv[j] = bf2f(xv8[j]);
        s += xv[j];
        sq += xv[j] * xv[j];
    }
    #pragma unroll
    for (int off = 32; off; off >>= 1) {
        s += __shfl_xor(s, off, 64);
        sq += __shfl_xor(sq, off, 64);
    }
    float mean = s * (1.f / 512.f);
    float var = sq * (1.f / 512.f) - mean * mean;
    float inv = rsqrtf(var + 1e-5f);
    const f32x4* gr = (const f32x4*)(gamma + lane * 8);
    const f32x4* br = (const f32x4*)(beta + lane * 8);
    f32x4 g0 = gr[0], g1 = gr[1];
    f32x4 b0 = br[0], b1 = br[1];
    f32x4 o0, o1;
    o0.x = (xv[0] - mean) * inv * g0.x + b0.x;
    o0.y = (xv[1] - mean) * inv * g0.y + b0.y;
    o0.z = (xv[2] - mean) * inv * g0.z + b0.z;
    o0.w = (xv[3] - mean) * inv * g0.w + b0.w;
    o1.x = (xv[4] - mean) * inv * g1.x + b1.x;
    o1.y = (xv[5] - mean) * inv * g1.y + b1.y;
    o1.z = (xv[6] - mean) * inv * g1.z + b1.z;
    o1.w = (xv[7] - mean) * inv * g1.w + b1.w;
    f32x4* orow = (f32x4*)(out + (size_t)row * 512 + lane * 8);
    orow[0] = o0;
    orow[1] = o1;
}

// ---------------------------------------------------------------------------
extern "C" void kernel_launch(void* const* d_in, const int* in_sizes, int n_in,
                              void* d_out, int out_size, void* d_ws, size_t ws_size,
                              hipStream_t stream) {
    const float* inQ = (const float*)d_in[0];
    const float* inK = (const float*)d_in[1];
    const float* inV = (const float*)d_in[2];
    const void* mask = d_in[3];
    const float* wq = (const float*)d_in[4];
    const float* wk = (const float*)d_in[5];
    const float* wv = (const float*)d_in[6];
    const float* wfc = (const float*)d_in[7];
    const float* gamma = (const float*)d_in[8];
    const float* beta = (const float*)d_in[9];
    float* out = (float*)d_out;
    char* ws = (char*)d_ws;

    short* Qp = (short*)(ws);                          // 8 MB
    short* Kp = (short*)(ws + (size_t)(8 << 20));      // 8 MB, fragment-major
    short* Vp = (short*)(ws + (size_t)(16 << 20));     // 8 MB, fragment-major
    short* ctx = (short*)(ws + (size_t)(24 << 20));    // 8 MB
    unsigned* mbits = (unsigned*)(ws + (size_t)(32 << 20)); // 2 MB
    short* wt = (short*)(ws + (size_t)(34 << 20));     // 2 MB: 4 x [512][512] bf16 [n][k]
    short* xb = (short*)(ws);                          // 8 MB bf16 x, reuses Qp (dead after attn)

    wprep_kernel<<<dim3(8, 8, 4), 256, 0, stream>>>(wq, wk, wv, wfc, wt);
    pack_mask_kernel<<<2048, 256, 0, stream>>>(mask, mbits);
    proj_kernel<<<dim3(128, 8, 3), 256, 0, stream>>>(inQ, inK, inV, wt, Qp, Kp, Vp);
    attn_kernel<<<dim3(64, 8, 4), 256, 0, stream>>>(
        Qp, Kp, Vp, (const unsigned long long*)mbits, ctx);
    fc_kernel<<<dim3(128, 8, 1), 256, 0, stream>>>(ctx, wt + 3 * 262144, inQ, xb);
    ln_kernel<<<2048, 256, 0, stream>>>(xb, gamma, beta, out);
}